// Round 1
// baseline (1290.534 us; speedup 1.0000x reference)
//
#include <hip/hip_runtime.h>
#include <cstdint>
#include <cstddef>

#define NH 12
#define HDIM 64
#define C_ 768
#define C3 2304
#define SEQ 1024
#define QSCALE 0.125f

// ---------------- GEMM: C[M,N] = A[M,K] @ B[K,N] + bias[N] ----------------
// BM=BN=128, BK=8, 256 threads, 8x8 per thread, fp32.
template<int N, int K>
__global__ __launch_bounds__(256)
void gemm_bias_kernel(const float* __restrict__ A, const float* __restrict__ B,
                      const float* __restrict__ bias, float* __restrict__ C)
{
    __shared__ float As[8][132];   // +4 pad: transposed-store conflict relief
    __shared__ float Bs[8][128];
    const int tid = threadIdx.x;
    const int tx = tid & 15;        // col block 0..15
    const int ty = tid >> 4;        // row block 0..15
    const int m0 = blockIdx.y * 128;
    const int n0 = blockIdx.x * 128;

    float acc[8][8];
#pragma unroll
    for (int i = 0; i < 8; ++i)
#pragma unroll
        for (int j = 0; j < 8; ++j) acc[i][j] = 0.f;

    const int arow = tid >> 1;          // 0..127
    const int acol = (tid & 1) * 4;     // 0 or 4
    const int bkq  = tid >> 5;          // 0..7
    const int bn   = (tid & 31) * 4;    // 0..124

    const float* Aptr = A + (size_t)(m0 + arow) * K + acol;
    const float* Bptr = B + (size_t)bkq * N + n0 + bn;

    for (int k0 = 0; k0 < K; k0 += 8) {
        float4 av = *(const float4*)(Aptr + k0);
        float4 bv = *(const float4*)(Bptr + (size_t)k0 * N);
        As[acol + 0][arow] = av.x;
        As[acol + 1][arow] = av.y;
        As[acol + 2][arow] = av.z;
        As[acol + 3][arow] = av.w;
        *(float4*)&Bs[bkq][bn] = bv;
        __syncthreads();
#pragma unroll
        for (int kk = 0; kk < 8; ++kk) {
            float a[8], b[8];
            *(float4*)&a[0] = *(const float4*)&As[kk][ty * 8];
            *(float4*)&a[4] = *(const float4*)&As[kk][ty * 8 + 4];
            *(float4*)&b[0] = *(const float4*)&Bs[kk][tx * 8];
            *(float4*)&b[4] = *(const float4*)&Bs[kk][tx * 8 + 4];
#pragma unroll
            for (int i = 0; i < 8; ++i)
#pragma unroll
                for (int j = 0; j < 8; ++j)
                    acc[i][j] = fmaf(a[i], b[j], acc[i][j]);
        }
        __syncthreads();
    }

    float bl[8];
    *(float4*)&bl[0] = *(const float4*)&bias[n0 + tx * 8];
    *(float4*)&bl[4] = *(const float4*)&bias[n0 + tx * 8 + 4];
#pragma unroll
    for (int i = 0; i < 8; ++i) {
        float* Crow = C + (size_t)(m0 + ty * 8 + i) * N + n0 + tx * 8;
        float4 c0 = { acc[i][0] + bl[0], acc[i][1] + bl[1],
                      acc[i][2] + bl[2], acc[i][3] + bl[3] };
        float4 c1 = { acc[i][4] + bl[4], acc[i][5] + bl[5],
                      acc[i][6] + bl[6], acc[i][7] + bl[7] };
        *(float4*)(Crow)     = c0;
        *(float4*)(Crow + 4) = c1;
    }
}

// ------------- decomposed rel-pos bias: out[bh][s][kc] = q[bh,s,:] . relpos[qc-kc+31,:] -------------
__global__ __launch_bounds__(256)
void relbias_kernel(const float* __restrict__ qkv, const float* __restrict__ relpos,
                    float* __restrict__ out, int isW)
{
    const int idx = blockIdx.x * 256 + threadIdx.x;   // [bh][s][kc]
    const int kc = idx & 31;
    const int s  = (idx >> 5) & 1023;
    const int bh = idx >> 15;                          // 0..95
    const int b = bh / NH, h = bh - b * NH;
    const int qc = isW ? (s & 31) : (s >> 5);
    const float* q = qkv + ((size_t)(b * SEQ + s)) * C3 + h * HDIM;   // q slice
    const float* r = relpos + (qc - kc + 31) * HDIM;
    float acc = 0.f;
#pragma unroll
    for (int d = 0; d < HDIM; d += 4) {
        float4 qv = *(const float4*)(q + d);
        float4 rv = *(const float4*)(r + d);
        acc = fmaf(qv.x, rv.x, acc);
        acc = fmaf(qv.y, rv.y, acc);
        acc = fmaf(qv.z, rv.z, acc);
        acc = fmaf(qv.w, rv.w, acc);
    }
    out[idx] = acc;
}

// ------------- flash attention with rel-pos bias -------------
// block = (b, h, 32 q-rows), 256 threads. K tiles of 64.
// thread (r2 = tid>>4, tg = tid&15) owns rows {r2, r2+16}, cols tg*4..tg*4+3.
__global__ __launch_bounds__(256)
void attn_kernel(const float* __restrict__ qkv, const float* __restrict__ biasH,
                 const float* __restrict__ biasW, float* __restrict__ out)
{
    __shared__ float qs[32 * 68];
    __shared__ float ksT[64 * 68];
    __shared__ float vs[64 * 64];
    __shared__ float ps[32 * 68];
    __shared__ float bhs[32 * 36];
    __shared__ float bws[32 * 36];

    const int tid = threadIdx.x;
    const int bh = blockIdx.y;
    const int b = bh / NH, h = bh - b * NH;
    const int s0 = blockIdx.x * 32;
    const int tg = tid & 15;
    const int r2 = tid >> 4;

    const size_t base = (size_t)b * SEQ * C3;

    // stage Q (pre-scaled) + this q-block's bias rows
    {
        const int row = tid >> 3, dq = (tid & 7) * 8;
        const float* qp = qkv + base + (size_t)(s0 + row) * C3 + h * HDIM + dq;
        float4 q0 = *(const float4*)qp;
        float4 q1 = *(const float4*)(qp + 4);
        float* dst = &qs[row * 68 + dq];
        float4 a = { q0.x * QSCALE, q0.y * QSCALE, q0.z * QSCALE, q0.w * QSCALE };
        float4 bq2 = { q1.x * QSCALE, q1.y * QSCALE, q1.z * QSCALE, q1.w * QSCALE };
        *(float4*)dst = a;
        *(float4*)(dst + 4) = bq2;
        const int bq = (tid & 7) * 4;
        *(float4*)&bhs[row * 36 + bq] =
            *(const float4*)&biasH[((size_t)bh * SEQ + s0 + row) * 32 + bq];
        *(float4*)&bws[row * 36 + bq] =
            *(const float4*)&biasW[((size_t)bh * SEQ + s0 + row) * 32 + bq];
    }

    float m0v = -3e38f, m1v = -3e38f, l0 = 0.f, l1 = 0.f;
    float4 o0 = {0,0,0,0}, o1 = {0,0,0,0};

    const int trow = tid >> 2;          // 0..63
    const int kd0 = (tid & 3) * 4;      // K staging col base
    const int vd0 = (tid & 3) * 16;     // V staging col base
    const int vsw = (trow & 7) * 4;     // V swizzle

    for (int t0 = 0; t0 < SEQ; t0 += 64) {
        __syncthreads();   // prev-tile PV done (also covers initial staging)
        // stage K^T: ksT[d][t], stride 68
        const float* kp = qkv + base + (size_t)(t0 + trow) * C3 + C_ + h * HDIM;
#pragma unroll
        for (int kq = 0; kq < 4; ++kq) {
            float4 kv = *(const float4*)(kp + kd0 + 16 * kq);
            const int c = kd0 + 16 * kq;
            ksT[(c + 0) * 68 + trow] = kv.x;
            ksT[(c + 1) * 68 + trow] = kv.y;
            ksT[(c + 2) * 68 + trow] = kv.z;
            ksT[(c + 3) * 68 + trow] = kv.w;
        }
        // stage V, XOR-swizzled columns
        const float* vp = qkv + base + (size_t)(t0 + trow) * C3 + 2 * C_ + h * HDIM;
#pragma unroll
        for (int kq = 0; kq < 4; ++kq) {
            float4 vv = *(const float4*)(vp + vd0 + 4 * kq);
            *(float4*)&vs[trow * 64 + ((vd0 + 4 * kq) ^ vsw)] = vv;
        }
        __syncthreads();

        // QK^T
        float4 c0 = {0,0,0,0}, c1 = {0,0,0,0};
#pragma unroll 8
        for (int d = 0; d < 64; ++d) {
            float4 kv = *(const float4*)&ksT[d * 68 + tg * 4];
            float qa = qs[r2 * 68 + d];
            float qb = qs[(r2 + 16) * 68 + d];
            c0.x = fmaf(qa, kv.x, c0.x); c0.y = fmaf(qa, kv.y, c0.y);
            c0.z = fmaf(qa, kv.z, c0.z); c0.w = fmaf(qa, kv.w, c0.w);
            c1.x = fmaf(qb, kv.x, c1.x); c1.y = fmaf(qb, kv.y, c1.y);
            c1.z = fmaf(qb, kv.z, c1.z); c1.w = fmaf(qb, kv.w, c1.w);
        }
        // add decomposed rel-pos bias
        const int khb = (t0 >> 5) + (tg >> 3);
        const float bha = bhs[r2 * 36 + khb];
        const float bhb = bhs[(r2 + 16) * 36 + khb];
        float4 bwa = *(const float4*)&bws[r2 * 36 + (tg & 7) * 4];
        float4 bwb = *(const float4*)&bws[(r2 + 16) * 36 + (tg & 7) * 4];
        c0.x += bha + bwa.x; c0.y += bha + bwa.y; c0.z += bha + bwa.z; c0.w += bha + bwa.w;
        c1.x += bhb + bwb.x; c1.y += bhb + bwb.y; c1.z += bhb + bwb.z; c1.w += bhb + bwb.w;

        // online softmax (row spread over 16 lanes)
        float tm0 = fmaxf(fmaxf(c0.x, c0.y), fmaxf(c0.z, c0.w));
        float tm1 = fmaxf(fmaxf(c1.x, c1.y), fmaxf(c1.z, c1.w));
#pragma unroll
        for (int off = 1; off < 16; off <<= 1) {
            tm0 = fmaxf(tm0, __shfl_xor(tm0, off));
            tm1 = fmaxf(tm1, __shfl_xor(tm1, off));
        }
        const float mn0 = fmaxf(m0v, tm0), mn1 = fmaxf(m1v, tm1);
        const float sc0 = __expf(m0v - mn0), sc1 = __expf(m1v - mn1);
        c0.x = __expf(c0.x - mn0); c0.y = __expf(c0.y - mn0);
        c0.z = __expf(c0.z - mn0); c0.w = __expf(c0.w - mn0);
        c1.x = __expf(c1.x - mn1); c1.y = __expf(c1.y - mn1);
        c1.z = __expf(c1.z - mn1); c1.w = __expf(c1.w - mn1);
        float ts0 = c0.x + c0.y + c0.z + c0.w;
        float ts1 = c1.x + c1.y + c1.z + c1.w;
#pragma unroll
        for (int off = 1; off < 16; off <<= 1) {
            ts0 += __shfl_xor(ts0, off);
            ts1 += __shfl_xor(ts1, off);
        }
        l0 = l0 * sc0 + ts0;  l1 = l1 * sc1 + ts1;
        m0v = mn0;            m1v = mn1;
        o0.x *= sc0; o0.y *= sc0; o0.z *= sc0; o0.w *= sc0;
        o1.x *= sc1; o1.y *= sc1; o1.z *= sc1; o1.w *= sc1;
        *(float4*)&ps[r2 * 68 + tg * 4] = c0;
        *(float4*)&ps[(r2 + 16) * 68 + tg * 4] = c1;
        __syncthreads();

        // PV
#pragma unroll 8
        for (int t = 0; t < 64; ++t) {
            float4 vv = *(const float4*)&vs[t * 64 + ((tg * 4) ^ ((t & 7) * 4))];
            float pa = ps[r2 * 68 + t];
            float pb = ps[(r2 + 16) * 68 + t];
            o0.x = fmaf(pa, vv.x, o0.x); o0.y = fmaf(pa, vv.y, o0.y);
            o0.z = fmaf(pa, vv.z, o0.z); o0.w = fmaf(pa, vv.w, o0.w);
            o1.x = fmaf(pb, vv.x, o1.x); o1.y = fmaf(pb, vv.y, o1.y);
            o1.z = fmaf(pb, vv.z, o1.z); o1.w = fmaf(pb, vv.w, o1.w);
        }
    }

    const float r0 = 1.f / l0, r1 = 1.f / l1;
    float4 w0 = { o0.x * r0, o0.y * r0, o0.z * r0, o0.w * r0 };
    float4 w1 = { o1.x * r1, o1.y * r1, o1.z * r1, o1.w * r1 };
    float* op0 = out + (size_t)(b * SEQ + s0 + r2) * C_ + h * HDIM + tg * 4;
    float* op1 = out + (size_t)(b * SEQ + s0 + r2 + 16) * C_ + h * HDIM + tg * 4;
    *(float4*)op0 = w0;
    *(float4*)op1 = w1;
}

extern "C" void kernel_launch(void* const* d_in, const int* in_sizes, int n_in,
                              void* d_out, int out_size, void* d_ws, size_t ws_size,
                              hipStream_t stream) {
    (void)in_sizes; (void)n_in; (void)out_size; (void)ws_size;
    const float* x      = (const float*)d_in[0];
    const float* w_qkv  = (const float*)d_in[1];
    const float* b_qkv  = (const float*)d_in[2];
    const float* w_proj = (const float*)d_in[3];
    const float* b_proj = (const float*)d_in[4];
    const float* rel_h  = (const float*)d_in[5];
    const float* rel_w  = (const float*)d_in[6];
    float* out = (float*)d_out;

    float* ws = (float*)d_ws;
    float* qkv     = ws;                                    // 8*1024*2304 = 18,874,368
    float* attnout = qkv + (size_t)8 * SEQ * C3;            // 8*1024*768  =  6,291,456
    float* biasH   = attnout + (size_t)8 * SEQ * C_;        // 96*1024*32  =  3,145,728
    float* biasW   = biasH + (size_t)96 * SEQ * 32;         // 96*1024*32

    // 1. qkv = x @ w_qkv + b_qkv
    {
        dim3 grid(C3 / 128, 8192 / 128);   // (18, 64)
        gemm_bias_kernel<C3, C_><<<grid, 256, 0, stream>>>(x, w_qkv, b_qkv, qkv);
    }
    // 2/3. decomposed rel-pos bias tables
    relbias_kernel<<<12288, 256, 0, stream>>>(qkv, rel_h, biasH, 0);
    relbias_kernel<<<12288, 256, 0, stream>>>(qkv, rel_w, biasW, 1);
    // 4. fused attention -> attnout[b][s][h*64+d]
    {
        dim3 grid(SEQ / 32, 96);
        attn_kernel<<<grid, 256, 0, stream>>>(qkv, biasH, biasW, attnout);
    }
    // 5. out = attnout @ w_proj + b_proj
    {
        dim3 grid(C_ / 128, 8192 / 128);   // (6, 64)
        gemm_bias_kernel<C_, C_><<<grid, 256, 0, stream>>>(attnout, w_proj, b_proj, out);
    }
}

// Round 2
// 993.199 us; speedup vs baseline: 1.2994x; 1.2994x over previous
//
#include <hip/hip_runtime.h>
#include <cstdint>
#include <cstddef>

#define NH 12
#define HDIM 64
#define C_ 768
#define C3 2304
#define SEQ 1024
#define QSCALE 0.125f
#define LS 72   // LDS row stride in bf16 elems (144B: 16B-aligned, bank-uniform)

typedef short bf16x8_t __attribute__((ext_vector_type(8)));
typedef float f32x4_t __attribute__((ext_vector_type(4)));
typedef unsigned short u16x4_t __attribute__((ext_vector_type(4)));

__device__ __forceinline__ unsigned short bf16_rne(float x) {
    unsigned int u = __float_as_uint(x);
    u += 0x7FFFu + ((u >> 16) & 1u);
    return (unsigned short)(u >> 16);
}
__device__ __forceinline__ float bf16f(unsigned short h) {
    return __uint_as_float(((unsigned int)h) << 16);
}

// ---------------- GEMM: C[M,N] = A[M,K] @ B[K,N] + bias[N] (fp32, unchanged) ----------------
template<int N, int K>
__global__ __launch_bounds__(256)
void gemm_bias_kernel(const float* __restrict__ A, const float* __restrict__ B,
                      const float* __restrict__ bias, float* __restrict__ C)
{
    __shared__ float As[8][132];
    __shared__ float Bs[8][128];
    const int tid = threadIdx.x;
    const int tx = tid & 15;
    const int ty = tid >> 4;
    const int m0 = blockIdx.y * 128;
    const int n0 = blockIdx.x * 128;

    float acc[8][8];
#pragma unroll
    for (int i = 0; i < 8; ++i)
#pragma unroll
        for (int j = 0; j < 8; ++j) acc[i][j] = 0.f;

    const int arow = tid >> 1;
    const int acol = (tid & 1) * 4;
    const int bkq  = tid >> 5;
    const int bn   = (tid & 31) * 4;

    const float* Aptr = A + (size_t)(m0 + arow) * K + acol;
    const float* Bptr = B + (size_t)bkq * N + n0 + bn;

    for (int k0 = 0; k0 < K; k0 += 8) {
        float4 av = *(const float4*)(Aptr + k0);
        float4 bv = *(const float4*)(Bptr + (size_t)k0 * N);
        As[acol + 0][arow] = av.x;
        As[acol + 1][arow] = av.y;
        As[acol + 2][arow] = av.z;
        As[acol + 3][arow] = av.w;
        *(float4*)&Bs[bkq][bn] = bv;
        __syncthreads();
#pragma unroll
        for (int kk = 0; kk < 8; ++kk) {
            float a[8], b[8];
            *(float4*)&a[0] = *(const float4*)&As[kk][ty * 8];
            *(float4*)&a[4] = *(const float4*)&As[kk][ty * 8 + 4];
            *(float4*)&b[0] = *(const float4*)&Bs[kk][tx * 8];
            *(float4*)&b[4] = *(const float4*)&Bs[kk][tx * 8 + 4];
#pragma unroll
            for (int i = 0; i < 8; ++i)
#pragma unroll
                for (int j = 0; j < 8; ++j)
                    acc[i][j] = fmaf(a[i], b[j], acc[i][j]);
        }
        __syncthreads();
    }

    float bl[8];
    *(float4*)&bl[0] = *(const float4*)&bias[n0 + tx * 8];
    *(float4*)&bl[4] = *(const float4*)&bias[n0 + tx * 8 + 4];
#pragma unroll
    for (int i = 0; i < 8; ++i) {
        float* Crow = C + (size_t)(m0 + ty * 8 + i) * N + n0 + tx * 8;
        float4 c0 = { acc[i][0] + bl[0], acc[i][1] + bl[1],
                      acc[i][2] + bl[2], acc[i][3] + bl[3] };
        float4 c1 = { acc[i][4] + bl[4], acc[i][5] + bl[5],
                      acc[i][6] + bl[6], acc[i][7] + bl[7] };
        *(float4*)(Crow)     = c0;
        *(float4*)(Crow + 4) = c1;
    }
}

// ------------- rel-pos bias tables (unchanged) -------------
__global__ __launch_bounds__(256)
void relbias_kernel(const float* __restrict__ qkv, const float* __restrict__ relpos,
                    float* __restrict__ out, int isW)
{
    const int idx = blockIdx.x * 256 + threadIdx.x;   // [bh][s][kc]
    const int kc = idx & 31;
    const int s  = (idx >> 5) & 1023;
    const int bh = idx >> 15;
    const int b = bh / NH, h = bh - b * NH;
    const int qc = isW ? (s & 31) : (s >> 5);
    const float* q = qkv + ((size_t)(b * SEQ + s)) * C3 + h * HDIM;
    const float* r = relpos + (qc - kc + 31) * HDIM;
    float acc = 0.f;
#pragma unroll
    for (int d = 0; d < HDIM; d += 4) {
        float4 qv = *(const float4*)(q + d);
        float4 rv = *(const float4*)(r + d);
        acc = fmaf(qv.x, rv.x, acc);
        acc = fmaf(qv.y, rv.y, acc);
        acc = fmaf(qv.z, rv.z, acc);
        acc = fmaf(qv.w, rv.w, acc);
    }
    out[idx] = acc;
}

// ------------- MFMA flash attention (bf16x3 split precision) -------------
// block = (bh, 64 q-rows), 4 waves; wave w owns q-rows [w*16, w*16+16), K-tiles of 64.
__global__ __launch_bounds__(256, 2)
void attn_mfma_kernel(const float* __restrict__ qkv, const float* __restrict__ biasH,
                      const float* __restrict__ biasW, float* __restrict__ out)
{
    __shared__ unsigned short khi[64 * LS], klo[64 * LS];
    __shared__ unsigned short vhi[64 * LS], vlo[64 * LS];   // V transposed: [d][t]
    __shared__ unsigned short phi[64 * LS], plo[64 * LS];
    __shared__ float bhs[64 * 33];

    const int tid  = threadIdx.x;
    const int bh   = blockIdx.y;
    const int b    = bh / NH, h = bh - b * NH;
    const int s0   = blockIdx.x * 64;
    const int w    = tid >> 6;
    const int lane = tid & 63;
    const int g    = lane >> 4;   // 0..3
    const int r    = lane & 15;   // 0..15

    const size_t base = (size_t)b * SEQ * C3 + (size_t)h * HDIM;
    const int st = tid >> 4;          // staging row base 0..15
    const int sd = (tid & 15) * 4;    // staging col base

    // ---- stage Q (pre-scaled) into khi/klo, and bias-H table ----
#pragma unroll
    for (int m = 0; m < 4; ++m) {
        const int row = st + 16 * m;
        float4 qv = *(const float4*)(qkv + base + (size_t)(s0 + row) * C3 + sd);
        qv.x *= QSCALE; qv.y *= QSCALE; qv.z *= QSCALE; qv.w *= QSCALE;
        u16x4_t hv, lv;
        hv.x = bf16_rne(qv.x); lv.x = bf16_rne(qv.x - bf16f(hv.x));
        hv.y = bf16_rne(qv.y); lv.y = bf16_rne(qv.y - bf16f(hv.y));
        hv.z = bf16_rne(qv.z); lv.z = bf16_rne(qv.z - bf16f(hv.z));
        hv.w = bf16_rne(qv.w); lv.w = bf16_rne(qv.w - bf16f(hv.w));
        *(u16x4_t*)&khi[row * LS + sd] = hv;
        *(u16x4_t*)&klo[row * LS + sd] = lv;
    }
    {
        const int q = tid >> 2, c0 = (tid & 3) * 8;
        const float* bp = biasH + ((size_t)bh * SEQ + s0 + q) * 32 + c0;
        *(float4*)&bhs[q * 33 + c0]     = *(const float4*)bp;
        *(float4*)&bhs[q * 33 + c0 + 4] = *(const float4*)(bp + 4);
    }
    __syncthreads();

    // Q fragments -> registers (A-frag: row = lane&15, k = c*32 + 8*(lane>>4) + j)
    bf16x8_t aqh[2], aql[2];
#pragma unroll
    for (int c = 0; c < 2; ++c) {
        aqh[c] = *(const bf16x8_t*)&khi[(w * 16 + r) * LS + c * 32 + 8 * g];
        aql[c] = *(const bf16x8_t*)&klo[(w * 16 + r) * LS + c * 32 + 8 * g];
    }
    // bias-W values for this lane's (q-row, kw) pairs
    float bw[4][2];
#pragma unroll
    for (int reg = 0; reg < 4; ++reg)
#pragma unroll
        for (int j = 0; j < 2; ++j)
            bw[reg][j] = biasW[((size_t)bh * SEQ + s0 + w * 16 + 4 * g + reg) * 32 + 16 * j + r];
    __syncthreads();

    f32x4_t oacc[4];
    float mrun[4], lrun[4];
#pragma unroll
    for (int i = 0; i < 4; ++i) {
        mrun[i] = -1e30f; lrun[i] = 0.f;
#pragma unroll
        for (int j = 0; j < 4; ++j) oacc[i][j] = 0.f;
    }

    for (int t0 = 0; t0 < SEQ; t0 += 64) {
        // ---- stage K tile (row-major) ----
#pragma unroll
        for (int m = 0; m < 4; ++m) {
            const int row = st + 16 * m;
            float4 kv = *(const float4*)(qkv + base + (size_t)(t0 + row) * C3 + C_ + sd);
            u16x4_t hv, lv;
            hv.x = bf16_rne(kv.x); lv.x = bf16_rne(kv.x - bf16f(hv.x));
            hv.y = bf16_rne(kv.y); lv.y = bf16_rne(kv.y - bf16f(hv.y));
            hv.z = bf16_rne(kv.z); lv.z = bf16_rne(kv.z - bf16f(hv.z));
            hv.w = bf16_rne(kv.w); lv.w = bf16_rne(kv.w - bf16f(hv.w));
            *(u16x4_t*)&khi[row * LS + sd] = hv;
            *(u16x4_t*)&klo[row * LS + sd] = lv;
        }
        // ---- stage V transposed via in-register 4x4 blocks: vT[d][t] ----
        {
            const int tb = (tid >> 4) * 4;       // t base 0..60
            const int d0 = (tid & 15) * 4;       // d base 0..60
            float4 rv[4];
#pragma unroll
            for (int i = 0; i < 4; ++i)
                rv[i] = *(const float4*)(qkv + base + (size_t)(t0 + tb + i) * C3 + 2 * C_ + d0);
#pragma unroll
            for (int c2 = 0; c2 < 4; ++c2) {
                const float f0 = ((const float*)&rv[0])[c2];
                const float f1 = ((const float*)&rv[1])[c2];
                const float f2 = ((const float*)&rv[2])[c2];
                const float f3 = ((const float*)&rv[3])[c2];
                u16x4_t hv, lv;
                hv.x = bf16_rne(f0); lv.x = bf16_rne(f0 - bf16f(hv.x));
                hv.y = bf16_rne(f1); lv.y = bf16_rne(f1 - bf16f(hv.y));
                hv.z = bf16_rne(f2); lv.z = bf16_rne(f2 - bf16f(hv.z));
                hv.w = bf16_rne(f3); lv.w = bf16_rne(f3 - bf16f(hv.w));
                *(u16x4_t*)&vhi[(d0 + c2) * LS + tb] = hv;
                *(u16x4_t*)&vlo[(d0 + c2) * LS + tb] = lv;
            }
        }
        __syncthreads();

        // ---- QK^T: S[16q x 64t], bf16x3 ----
        f32x4_t sacc[4];
#pragma unroll
        for (int fj = 0; fj < 4; ++fj)
#pragma unroll
            for (int j = 0; j < 4; ++j) sacc[fj][j] = 0.f;
#pragma unroll
        for (int c = 0; c < 2; ++c)
#pragma unroll
            for (int fj = 0; fj < 4; ++fj) {
                bf16x8_t bkh = *(const bf16x8_t*)&khi[(16 * fj + r) * LS + c * 32 + 8 * g];
                bf16x8_t bkl = *(const bf16x8_t*)&klo[(16 * fj + r) * LS + c * 32 + 8 * g];
                sacc[fj] = __builtin_amdgcn_mfma_f32_16x16x32_bf16(aqh[c], bkh, sacc[fj], 0, 0, 0);
                sacc[fj] = __builtin_amdgcn_mfma_f32_16x16x32_bf16(aqh[c], bkl, sacc[fj], 0, 0, 0);
                sacc[fj] = __builtin_amdgcn_mfma_f32_16x16x32_bf16(aql[c], bkh, sacc[fj], 0, 0, 0);
            }
        // ---- add decomposed rel-pos bias (D-layout: row q = 4g+reg, col t = t0+16fj+r) ----
        const int kh0 = t0 >> 5;
#pragma unroll
        for (int fj = 0; fj < 4; ++fj)
#pragma unroll
            for (int reg = 0; reg < 4; ++reg)
                sacc[fj][reg] += bhs[(w * 16 + 4 * g + reg) * 33 + kh0 + (fj >> 1)] + bw[reg][fj & 1];

        // ---- online softmax: 4 q-rows per lane, 16-lane butterfly over t ----
#pragma unroll
        for (int reg = 0; reg < 4; ++reg) {
            float tm = fmaxf(fmaxf(sacc[0][reg], sacc[1][reg]),
                             fmaxf(sacc[2][reg], sacc[3][reg]));
#pragma unroll
            for (int off = 1; off < 16; off <<= 1) tm = fmaxf(tm, __shfl_xor(tm, off));
            const float mn = fmaxf(mrun[reg], tm);
            const float sc = __expf(mrun[reg] - mn);
            mrun[reg] = mn;
            float rs = 0.f;
#pragma unroll
            for (int fj = 0; fj < 4; ++fj) {
                const float e = __expf(sacc[fj][reg] - mn);
                sacc[fj][reg] = e;
                rs += e;
            }
#pragma unroll
            for (int off = 1; off < 16; off <<= 1) rs += __shfl_xor(rs, off);
            lrun[reg] = lrun[reg] * sc + rs;
#pragma unroll
            for (int fd = 0; fd < 4; ++fd) oacc[fd][reg] *= sc;
        }
        // ---- store P hi/lo (wave-private rows) ----
#pragma unroll
        for (int fj = 0; fj < 4; ++fj)
#pragma unroll
            for (int reg = 0; reg < 4; ++reg) {
                const float e = sacc[fj][reg];
                const unsigned short ph = bf16_rne(e);
                const unsigned short pl = bf16_rne(e - bf16f(ph));
                const int addr = (w * 16 + 4 * g + reg) * LS + 16 * fj + r;
                phi[addr] = ph;
                plo[addr] = pl;
            }
        asm volatile("s_waitcnt lgkmcnt(0)" ::: "memory");

        // ---- PV: O += P @ V, bf16x3 ----
#pragma unroll
        for (int c = 0; c < 2; ++c) {
            bf16x8_t aph = *(const bf16x8_t*)&phi[(w * 16 + r) * LS + c * 32 + 8 * g];
            bf16x8_t apl = *(const bf16x8_t*)&plo[(w * 16 + r) * LS + c * 32 + 8 * g];
#pragma unroll
            for (int fd = 0; fd < 4; ++fd) {
                bf16x8_t bvh = *(const bf16x8_t*)&vhi[(16 * fd + r) * LS + c * 32 + 8 * g];
                bf16x8_t bvl = *(const bf16x8_t*)&vlo[(16 * fd + r) * LS + c * 32 + 8 * g];
                oacc[fd] = __builtin_amdgcn_mfma_f32_16x16x32_bf16(aph, bvh, oacc[fd], 0, 0, 0);
                oacc[fd] = __builtin_amdgcn_mfma_f32_16x16x32_bf16(aph, bvl, oacc[fd], 0, 0, 0);
                oacc[fd] = __builtin_amdgcn_mfma_f32_16x16x32_bf16(apl, bvh, oacc[fd], 0, 0, 0);
            }
        }
        __syncthreads();
    }

    // ---- epilogue: normalize + store ----
#pragma unroll
    for (int reg = 0; reg < 4; ++reg) {
        const float rinv = 1.f / lrun[reg];
        const int qrow = s0 + w * 16 + 4 * g + reg;
        float* op = out + ((size_t)b * SEQ + qrow) * C_ + h * HDIM;
#pragma unroll
        for (int fd = 0; fd < 4; ++fd)
            op[16 * fd + r] = oacc[fd][reg] * rinv;
    }
}

extern "C" void kernel_launch(void* const* d_in, const int* in_sizes, int n_in,
                              void* d_out, int out_size, void* d_ws, size_t ws_size,
                              hipStream_t stream) {
    (void)in_sizes; (void)n_in; (void)out_size; (void)ws_size;
    const float* x      = (const float*)d_in[0];
    const float* w_qkv  = (const float*)d_in[1];
    const float* b_qkv  = (const float*)d_in[2];
    const float* w_proj = (const float*)d_in[3];
    const float* b_proj = (const float*)d_in[4];
    const float* rel_h  = (const float*)d_in[5];
    const float* rel_w  = (const float*)d_in[6];
    float* out = (float*)d_out;

    float* ws = (float*)d_ws;
    float* qkv     = ws;
    float* attnout = qkv + (size_t)8 * SEQ * C3;
    float* biasH   = attnout + (size_t)8 * SEQ * C_;
    float* biasW   = biasH + (size_t)96 * SEQ * 32;

    // 1. qkv = x @ w_qkv + b_qkv
    {
        dim3 grid(C3 / 128, 8192 / 128);
        gemm_bias_kernel<C3, C_><<<grid, 256, 0, stream>>>(x, w_qkv, b_qkv, qkv);
    }
    // 2/3. rel-pos bias tables
    relbias_kernel<<<12288, 256, 0, stream>>>(qkv, rel_h, biasH, 0);
    relbias_kernel<<<12288, 256, 0, stream>>>(qkv, rel_w, biasW, 1);
    // 4. MFMA flash attention
    {
        dim3 grid(SEQ / 64, 96);
        attn_mfma_kernel<<<grid, 256, 0, stream>>>(qkv, biasH, biasW, attnout);
    }
    // 5. out = attnout @ w_proj + b_proj
    {
        dim3 grid(C_ / 128, 8192 / 128);
        gemm_bias_kernel<C_, C_><<<grid, 256, 0, stream>>>(attnout, w_proj, b_proj, out);
    }
}

// Round 3
// 595.341 us; speedup vs baseline: 2.1677x; 1.6683x over previous
//
#include <hip/hip_runtime.h>
#include <cstdint>
#include <cstddef>

#define NH 12
#define HDIM 64
#define C_ 768
#define C3 2304
#define SEQ 1024
#define QSCALE 0.125f
#define LS 72   // LDS row stride in bf16 elems (144B)

typedef short bf16x8_t __attribute__((ext_vector_type(8)));
typedef float f32x4_t __attribute__((ext_vector_type(4)));
typedef unsigned short u16x4_t __attribute__((ext_vector_type(4)));

__device__ __forceinline__ unsigned short bf16_rne(float x) {
    unsigned int u = __float_as_uint(x);
    u += 0x7FFFu + ((u >> 16) & 1u);
    return (unsigned short)(u >> 16);
}
__device__ __forceinline__ float bf16f(unsigned short h) {
    return __uint_as_float(((unsigned int)h) << 16);
}

// ---------------- split: fp32 -> hi/lo bf16 (elementwise) ----------------
__global__ __launch_bounds__(256)
void split_kernel(const float* __restrict__ in, unsigned short* __restrict__ hi,
                  unsigned short* __restrict__ lo)
{
    const int i = blockIdx.x * 256 + threadIdx.x;
    float4 v = ((const float4*)in)[i];
    u16x4_t h, l;
    h.x = bf16_rne(v.x); l.x = bf16_rne(v.x - bf16f(h.x));
    h.y = bf16_rne(v.y); l.y = bf16_rne(v.y - bf16f(h.y));
    h.z = bf16_rne(v.z); l.z = bf16_rne(v.z - bf16f(h.z));
    h.w = bf16_rne(v.w); l.w = bf16_rne(v.w - bf16f(h.w));
    ((u16x4_t*)hi)[i] = h;
    ((u16x4_t*)lo)[i] = l;
}

// ---------------- splitT: W[K][N] fp32 -> WT hi/lo [N][K] bf16 ----------------
__global__ __launch_bounds__(256)
void splitT_kernel(const float* __restrict__ W, unsigned short* __restrict__ Thi,
                   unsigned short* __restrict__ Tlo, int Kdim, int Ndim)
{
    __shared__ float tile[32][33];
    const int t = threadIdx.x;
    const int kb = blockIdx.y * 32, nb = blockIdx.x * 32;
    const int lr = t >> 3, lc = (t & 7) * 4;
    *(float4*)&tile[lr][lc] = *(const float4*)&W[(size_t)(kb + lr) * Ndim + nb + lc];
    __syncthreads();
    const float v0 = tile[lc + 0][lr];
    const float v1 = tile[lc + 1][lr];
    const float v2 = tile[lc + 2][lr];
    const float v3 = tile[lc + 3][lr];
    u16x4_t h, l;
    h.x = bf16_rne(v0); l.x = bf16_rne(v0 - bf16f(h.x));
    h.y = bf16_rne(v1); l.y = bf16_rne(v1 - bf16f(h.y));
    h.z = bf16_rne(v2); l.z = bf16_rne(v2 - bf16f(h.z));
    h.w = bf16_rne(v3); l.w = bf16_rne(v3 - bf16f(h.w));
    *(u16x4_t*)&Thi[(size_t)(nb + lr) * Kdim + kb + lc] = h;
    *(u16x4_t*)&Tlo[(size_t)(nb + lr) * Kdim + kb + lc] = l;
}

// ---------------- MFMA GEMM: C[M,N] = A[M,768] @ BT[N,768]^T + bias, bf16x3 ----------------
// 128x128 tile, BK=32, 4 waves each 64x64.  LDS rows: [32 hi | 32 lo | 8 pad].
template<int N>
__global__ __launch_bounds__(256, 2)
void gemm_mfma_kernel(const unsigned short* __restrict__ Ahi, const unsigned short* __restrict__ Alo,
                      const unsigned short* __restrict__ BThi, const unsigned short* __restrict__ BTlo,
                      const float* __restrict__ bias, float* __restrict__ C)
{
    constexpr int K = 768;
    __shared__ unsigned short As[128 * LS];
    __shared__ unsigned short Bs[128 * LS];
    const int tid = threadIdx.x;
    const int w = tid >> 6, lane = tid & 63, g = lane >> 4, r = lane & 15;
    const int wr = (w >> 1) * 64, wc = (w & 1) * 64;
    const int m0 = blockIdx.y * 128, n0 = blockIdx.x * 128;
    const int srow = tid >> 1, sh = (tid & 1) * 16;

    const unsigned short* aH = Ahi + (size_t)(m0 + srow) * K + sh;
    const unsigned short* aL = Alo + (size_t)(m0 + srow) * K + sh;
    const unsigned short* bH = BThi + (size_t)(n0 + srow) * K + sh;
    const unsigned short* bL = BTlo + (size_t)(n0 + srow) * K + sh;

    f32x4_t acc[4][4];
#pragma unroll
    for (int i = 0; i < 4; ++i)
#pragma unroll
        for (int j = 0; j < 4; ++j)
#pragma unroll
            for (int q = 0; q < 4; ++q) acc[i][j][q] = 0.f;

    for (int k0 = 0; k0 < K; k0 += 32) {
        bf16x8_t va0 = *(const bf16x8_t*)(aH + k0);
        bf16x8_t va1 = *(const bf16x8_t*)(aH + k0 + 8);
        bf16x8_t wa0 = *(const bf16x8_t*)(aL + k0);
        bf16x8_t wa1 = *(const bf16x8_t*)(aL + k0 + 8);
        bf16x8_t vb0 = *(const bf16x8_t*)(bH + k0);
        bf16x8_t vb1 = *(const bf16x8_t*)(bH + k0 + 8);
        bf16x8_t wb0 = *(const bf16x8_t*)(bL + k0);
        bf16x8_t wb1 = *(const bf16x8_t*)(bL + k0 + 8);
        __syncthreads();   // prior iteration's fragment reads complete
        *(bf16x8_t*)&As[srow * LS + sh]          = va0;
        *(bf16x8_t*)&As[srow * LS + sh + 8]      = va1;
        *(bf16x8_t*)&As[srow * LS + 32 + sh]     = wa0;
        *(bf16x8_t*)&As[srow * LS + 32 + sh + 8] = wa1;
        *(bf16x8_t*)&Bs[srow * LS + sh]          = vb0;
        *(bf16x8_t*)&Bs[srow * LS + sh + 8]      = vb1;
        *(bf16x8_t*)&Bs[srow * LS + 32 + sh]     = wb0;
        *(bf16x8_t*)&Bs[srow * LS + 32 + sh + 8] = wb1;
        __syncthreads();
        bf16x8_t amh[4], aml[4];
#pragma unroll
        for (int i = 0; i < 4; ++i) {
            amh[i] = *(const bf16x8_t*)&As[(wr + 16 * i + r) * LS + 8 * g];
            aml[i] = *(const bf16x8_t*)&As[(wr + 16 * i + r) * LS + 32 + 8 * g];
        }
#pragma unroll
        for (int j = 0; j < 4; ++j) {
            bf16x8_t bnh = *(const bf16x8_t*)&Bs[(wc + 16 * j + r) * LS + 8 * g];
            bf16x8_t bnl = *(const bf16x8_t*)&Bs[(wc + 16 * j + r) * LS + 32 + 8 * g];
#pragma unroll
            for (int i = 0; i < 4; ++i) {
                acc[i][j] = __builtin_amdgcn_mfma_f32_16x16x32_bf16(amh[i], bnh, acc[i][j], 0, 0, 0);
                acc[i][j] = __builtin_amdgcn_mfma_f32_16x16x32_bf16(amh[i], bnl, acc[i][j], 0, 0, 0);
                acc[i][j] = __builtin_amdgcn_mfma_f32_16x16x32_bf16(aml[i], bnh, acc[i][j], 0, 0, 0);
            }
        }
    }

    // epilogue: bias + store (D-layout: row m = 4g+q, col n = r)
#pragma unroll
    for (int j = 0; j < 4; ++j) {
        const float bj = bias[n0 + wc + 16 * j + r];
#pragma unroll
        for (int i = 0; i < 4; ++i) {
            float* Cp = C + (size_t)(m0 + wr + 16 * i + 4 * g) * N + n0 + wc + 16 * j + r;
#pragma unroll
            for (int q = 0; q < 4; ++q)
                Cp[(size_t)q * N] = acc[i][j][q] + bj;
        }
    }
}

// ------------- rel-pos bias tables -------------
__global__ __launch_bounds__(256)
void relbias_kernel(const float* __restrict__ qkv, const float* __restrict__ relpos,
                    float* __restrict__ out, int isW)
{
    const int idx = blockIdx.x * 256 + threadIdx.x;   // [bh][s][kc]
    const int kc = idx & 31;
    const int s  = (idx >> 5) & 1023;
    const int bh = idx >> 15;
    const int b = bh / NH, h = bh - b * NH;
    const int qc = isW ? (s & 31) : (s >> 5);
    const float* q = qkv + ((size_t)(b * SEQ + s)) * C3 + h * HDIM;
    const float* r = relpos + (qc - kc + 31) * HDIM;
    float acc = 0.f;
#pragma unroll
    for (int d = 0; d < HDIM; d += 4) {
        float4 qv = *(const float4*)(q + d);
        float4 rv = *(const float4*)(r + d);
        acc = fmaf(qv.x, rv.x, acc);
        acc = fmaf(qv.y, rv.y, acc);
        acc = fmaf(qv.z, rv.z, acc);
        acc = fmaf(qv.w, rv.w, acc);
    }
    out[idx] = acc;
}

// ------------- MFMA flash attention (bf16x3), writes hi/lo bf16 output -------------
__global__ __launch_bounds__(256, 2)
void attn_mfma_kernel(const float* __restrict__ qkv, const float* __restrict__ biasH,
                      const float* __restrict__ biasW,
                      unsigned short* __restrict__ outh, unsigned short* __restrict__ outl)
{
    __shared__ unsigned short khi[64 * LS], klo[64 * LS];
    __shared__ unsigned short vhi[64 * LS], vlo[64 * LS];   // V transposed: [d][t]
    __shared__ unsigned short phi[64 * LS], plo[64 * LS];
    __shared__ float bhs[64 * 33];

    const int tid  = threadIdx.x;
    const int bh   = blockIdx.y;
    const int b    = bh / NH, h = bh - b * NH;
    const int s0   = blockIdx.x * 64;
    const int w    = tid >> 6;
    const int lane = tid & 63;
    const int g    = lane >> 4;
    const int r    = lane & 15;

    const size_t base = (size_t)b * SEQ * C3 + (size_t)h * HDIM;
    const int st = tid >> 4;
    const int sd = (tid & 15) * 4;

    // ---- stage Q (pre-scaled) into khi/klo, and bias-H table ----
#pragma unroll
    for (int m = 0; m < 4; ++m) {
        const int row = st + 16 * m;
        float4 qv = *(const float4*)(qkv + base + (size_t)(s0 + row) * C3 + sd);
        qv.x *= QSCALE; qv.y *= QSCALE; qv.z *= QSCALE; qv.w *= QSCALE;
        u16x4_t hv, lv;
        hv.x = bf16_rne(qv.x); lv.x = bf16_rne(qv.x - bf16f(hv.x));
        hv.y = bf16_rne(qv.y); lv.y = bf16_rne(qv.y - bf16f(hv.y));
        hv.z = bf16_rne(qv.z); lv.z = bf16_rne(qv.z - bf16f(hv.z));
        hv.w = bf16_rne(qv.w); lv.w = bf16_rne(qv.w - bf16f(hv.w));
        *(u16x4_t*)&khi[row * LS + sd] = hv;
        *(u16x4_t*)&klo[row * LS + sd] = lv;
    }
    {
        const int q = tid >> 2, c0 = (tid & 3) * 8;
        const float* bp = biasH + ((size_t)bh * SEQ + s0 + q) * 32 + c0;
        *(float4*)&bhs[q * 33 + c0]     = *(const float4*)bp;
        *(float4*)&bhs[q * 33 + c0 + 4] = *(const float4*)(bp + 4);
    }
    __syncthreads();

    bf16x8_t aqh[2], aql[2];
#pragma unroll
    for (int c = 0; c < 2; ++c) {
        aqh[c] = *(const bf16x8_t*)&khi[(w * 16 + r) * LS + c * 32 + 8 * g];
        aql[c] = *(const bf16x8_t*)&klo[(w * 16 + r) * LS + c * 32 + 8 * g];
    }
    float bw[4][2];
#pragma unroll
    for (int reg = 0; reg < 4; ++reg)
#pragma unroll
        for (int j = 0; j < 2; ++j)
            bw[reg][j] = biasW[((size_t)bh * SEQ + s0 + w * 16 + 4 * g + reg) * 32 + 16 * j + r];
    __syncthreads();

    f32x4_t oacc[4];
    float mrun[4], lrun[4];
#pragma unroll
    for (int i = 0; i < 4; ++i) {
        mrun[i] = -1e30f; lrun[i] = 0.f;
#pragma unroll
        for (int j = 0; j < 4; ++j) oacc[i][j] = 0.f;
    }

    for (int t0 = 0; t0 < SEQ; t0 += 64) {
        // ---- stage K tile (row-major) ----
#pragma unroll
        for (int m = 0; m < 4; ++m) {
            const int row = st + 16 * m;
            float4 kv = *(const float4*)(qkv + base + (size_t)(t0 + row) * C3 + C_ + sd);
            u16x4_t hv, lv;
            hv.x = bf16_rne(kv.x); lv.x = bf16_rne(kv.x - bf16f(hv.x));
            hv.y = bf16_rne(kv.y); lv.y = bf16_rne(kv.y - bf16f(hv.y));
            hv.z = bf16_rne(kv.z); lv.z = bf16_rne(kv.z - bf16f(hv.z));
            hv.w = bf16_rne(kv.w); lv.w = bf16_rne(kv.w - bf16f(hv.w));
            *(u16x4_t*)&khi[row * LS + sd] = hv;
            *(u16x4_t*)&klo[row * LS + sd] = lv;
        }
        // ---- stage V transposed via in-register 4x4 blocks: vT[d][t] ----
        {
            const int tb = (tid >> 4) * 4;
            const int d0 = (tid & 15) * 4;
            float4 rv[4];
#pragma unroll
            for (int i = 0; i < 4; ++i)
                rv[i] = *(const float4*)(qkv + base + (size_t)(t0 + tb + i) * C3 + 2 * C_ + d0);
#pragma unroll
            for (int c2 = 0; c2 < 4; ++c2) {
                const float f0 = ((const float*)&rv[0])[c2];
                const float f1 = ((const float*)&rv[1])[c2];
                const float f2 = ((const float*)&rv[2])[c2];
                const float f3 = ((const float*)&rv[3])[c2];
                u16x4_t hv, lv;
                hv.x = bf16_rne(f0); lv.x = bf16_rne(f0 - bf16f(hv.x));
                hv.y = bf16_rne(f1); lv.y = bf16_rne(f1 - bf16f(hv.y));
                hv.z = bf16_rne(f2); lv.z = bf16_rne(f2 - bf16f(hv.z));
                hv.w = bf16_rne(f3); lv.w = bf16_rne(f3 - bf16f(hv.w));
                *(u16x4_t*)&vhi[(d0 + c2) * LS + tb] = hv;
                *(u16x4_t*)&vlo[(d0 + c2) * LS + tb] = lv;
            }
        }
        __syncthreads();

        // ---- QK^T ----
        f32x4_t sacc[4];
#pragma unroll
        for (int fj = 0; fj < 4; ++fj)
#pragma unroll
            for (int j = 0; j < 4; ++j) sacc[fj][j] = 0.f;
#pragma unroll
        for (int c = 0; c < 2; ++c)
#pragma unroll
            for (int fj = 0; fj < 4; ++fj) {
                bf16x8_t bkh = *(const bf16x8_t*)&khi[(16 * fj + r) * LS + c * 32 + 8 * g];
                bf16x8_t bkl = *(const bf16x8_t*)&klo[(16 * fj + r) * LS + c * 32 + 8 * g];
                sacc[fj] = __builtin_amdgcn_mfma_f32_16x16x32_bf16(aqh[c], bkh, sacc[fj], 0, 0, 0);
                sacc[fj] = __builtin_amdgcn_mfma_f32_16x16x32_bf16(aqh[c], bkl, sacc[fj], 0, 0, 0);
                sacc[fj] = __builtin_amdgcn_mfma_f32_16x16x32_bf16(aql[c], bkh, sacc[fj], 0, 0, 0);
            }
        const int kh0 = t0 >> 5;
#pragma unroll
        for (int fj = 0; fj < 4; ++fj)
#pragma unroll
            for (int reg = 0; reg < 4; ++reg)
                sacc[fj][reg] += bhs[(w * 16 + 4 * g + reg) * 33 + kh0 + (fj >> 1)] + bw[reg][fj & 1];

        // ---- online softmax ----
#pragma unroll
        for (int reg = 0; reg < 4; ++reg) {
            float tm = fmaxf(fmaxf(sacc[0][reg], sacc[1][reg]),
                             fmaxf(sacc[2][reg], sacc[3][reg]));
#pragma unroll
            for (int off = 1; off < 16; off <<= 1) tm = fmaxf(tm, __shfl_xor(tm, off));
            const float mn = fmaxf(mrun[reg], tm);
            const float sc = __expf(mrun[reg] - mn);
            mrun[reg] = mn;
            float rs = 0.f;
#pragma unroll
            for (int fj = 0; fj < 4; ++fj) {
                const float e = __expf(sacc[fj][reg] - mn);
                sacc[fj][reg] = e;
                rs += e;
            }
#pragma unroll
            for (int off = 1; off < 16; off <<= 1) rs += __shfl_xor(rs, off);
            lrun[reg] = lrun[reg] * sc + rs;
#pragma unroll
            for (int fd = 0; fd < 4; ++fd) oacc[fd][reg] *= sc;
        }
#pragma unroll
        for (int fj = 0; fj < 4; ++fj)
#pragma unroll
            for (int reg = 0; reg < 4; ++reg) {
                const float e = sacc[fj][reg];
                const unsigned short ph = bf16_rne(e);
                const unsigned short pl = bf16_rne(e - bf16f(ph));
                const int addr = (w * 16 + 4 * g + reg) * LS + 16 * fj + r;
                phi[addr] = ph;
                plo[addr] = pl;
            }
        asm volatile("s_waitcnt lgkmcnt(0)" ::: "memory");

        // ---- PV ----
#pragma unroll
        for (int c = 0; c < 2; ++c) {
            bf16x8_t aph = *(const bf16x8_t*)&phi[(w * 16 + r) * LS + c * 32 + 8 * g];
            bf16x8_t apl = *(const bf16x8_t*)&plo[(w * 16 + r) * LS + c * 32 + 8 * g];
#pragma unroll
            for (int fd = 0; fd < 4; ++fd) {
                bf16x8_t bvh = *(const bf16x8_t*)&vhi[(16 * fd + r) * LS + c * 32 + 8 * g];
                bf16x8_t bvl = *(const bf16x8_t*)&vlo[(16 * fd + r) * LS + c * 32 + 8 * g];
                oacc[fd] = __builtin_amdgcn_mfma_f32_16x16x32_bf16(aph, bvh, oacc[fd], 0, 0, 0);
                oacc[fd] = __builtin_amdgcn_mfma_f32_16x16x32_bf16(aph, bvl, oacc[fd], 0, 0, 0);
                oacc[fd] = __builtin_amdgcn_mfma_f32_16x16x32_bf16(apl, bvh, oacc[fd], 0, 0, 0);
            }
        }
        __syncthreads();
    }

    // ---- epilogue: normalize + split-store ----
#pragma unroll
    for (int reg = 0; reg < 4; ++reg) {
        const float rinv = 1.f / lrun[reg];
        const int qrow = s0 + w * 16 + 4 * g + reg;
        unsigned short* oph = outh + ((size_t)b * SEQ + qrow) * C_ + h * HDIM;
        unsigned short* opl = outl + ((size_t)b * SEQ + qrow) * C_ + h * HDIM;
#pragma unroll
        for (int fd = 0; fd < 4; ++fd) {
            const float v = oacc[fd][reg] * rinv;
            const unsigned short hv = bf16_rne(v);
            oph[16 * fd + r] = hv;
            opl[16 * fd + r] = bf16_rne(v - bf16f(hv));
        }
    }
}

extern "C" void kernel_launch(void* const* d_in, const int* in_sizes, int n_in,
                              void* d_out, int out_size, void* d_ws, size_t ws_size,
                              hipStream_t stream) {
    (void)in_sizes; (void)n_in; (void)out_size; (void)ws_size;
    const float* x      = (const float*)d_in[0];
    const float* w_qkv  = (const float*)d_in[1];
    const float* b_qkv  = (const float*)d_in[2];
    const float* w_proj = (const float*)d_in[3];
    const float* b_proj = (const float*)d_in[4];
    const float* rel_h  = (const float*)d_in[5];
    const float* rel_w  = (const float*)d_in[6];
    float* out = (float*)d_out;

    char* base = (char*)d_ws;
    float*          qkv   = (float*)base;                       // 75,497,472 B
    unsigned short* xhi   = (unsigned short*)(base + 75497472); // 12,582,912 B
    unsigned short* xlo   = (unsigned short*)(base + 88080384); // 12,582,912 B
    unsigned short* wqh   = (unsigned short*)(base + 100663296);//  3,538,944 B
    unsigned short* wql   = (unsigned short*)(base + 104202240);
    unsigned short* wph   = (unsigned short*)(base + 107741184);//  1,179,648 B
    unsigned short* wpl   = (unsigned short*)(base + 108920832);
    float*          biasH = (float*)(base + 110100480);         // 12,582,912 B
    float*          biasW = (float*)(base + 122683392);
    // after QKV GEMM, x splits are dead -> reuse as attn output hi/lo
    unsigned short* ohif  = xhi;
    unsigned short* olo   = xlo;

    // 1. split x -> hi/lo   (8*1024*768 = 6,291,456 elems / 4 per thread)
    split_kernel<<<6144, 256, 0, stream>>>(x, xhi, xlo);
    // 2. transpose+split weights
    {
        dim3 gq(C3 / 32, C_ / 32);   // (72,24)
        splitT_kernel<<<gq, 256, 0, stream>>>(w_qkv, wqh, wql, C_, C3);
        dim3 gp(C_ / 32, C_ / 32);   // (24,24)
        splitT_kernel<<<gp, 256, 0, stream>>>(w_proj, wph, wpl, C_, C_);
    }
    // 3. qkv = x @ w_qkv + b_qkv  (MFMA bf16x3)
    {
        dim3 grid(C3 / 128, 8192 / 128);   // (18, 64)
        gemm_mfma_kernel<C3><<<grid, 256, 0, stream>>>(xhi, xlo, wqh, wql, b_qkv, qkv);
    }
    // 4/5. rel-pos bias tables
    relbias_kernel<<<12288, 256, 0, stream>>>(qkv, rel_h, biasH, 0);
    relbias_kernel<<<12288, 256, 0, stream>>>(qkv, rel_w, biasW, 1);
    // 6. MFMA flash attention -> split hi/lo output
    {
        dim3 grid(SEQ / 64, 96);
        attn_mfma_kernel<<<grid, 256, 0, stream>>>(qkv, biasH, biasW, ohif, olo);
    }
    // 7. out = attnout @ w_proj + b_proj  (MFMA bf16x3)
    {
        dim3 grid(C_ / 128, 8192 / 128);   // (6, 64)
        gemm_mfma_kernel<C_><<<grid, 256, 0, stream>>>(ohif, olo, wph, wpl, b_proj, out);
    }
}

// Round 6
// 536.932 us; speedup vs baseline: 2.4035x; 1.1088x over previous
//
#include <hip/hip_runtime.h>
#include <cstdint>
#include <cstddef>

#define NH 12
#define HDIM 64
#define C_ 768
#define C3 2304
#define SEQ 1024
#define LS 72    // K/V LDS row stride in bf16 elems (144B, 16B-aligned)

typedef short bf16x8_t __attribute__((ext_vector_type(8)));
typedef float f32x4_t __attribute__((ext_vector_type(4)));
typedef unsigned short u16x4_t __attribute__((ext_vector_type(4)));

__device__ __forceinline__ unsigned short bf16_rne(float x) {
    unsigned int u = __float_as_uint(x);
    u += 0x7FFFu + ((u >> 16) & 1u);
    return (unsigned short)(u >> 16);
}
__device__ __forceinline__ float bf16f(unsigned short h) {
    return __uint_as_float(((unsigned int)h) << 16);
}

// ---------------- split: fp32 -> hi/lo bf16 (elementwise) ----------------
__global__ __launch_bounds__(256)
void split_kernel(const float* __restrict__ in, unsigned short* __restrict__ hi,
                  unsigned short* __restrict__ lo)
{
    const int i = blockIdx.x * 256 + threadIdx.x;
    float4 v = ((const float4*)in)[i];
    u16x4_t h, l;
    h.x = bf16_rne(v.x); l.x = bf16_rne(v.x - bf16f(h.x));
    h.y = bf16_rne(v.y); l.y = bf16_rne(v.y - bf16f(h.y));
    h.z = bf16_rne(v.z); l.z = bf16_rne(v.z - bf16f(h.z));
    h.w = bf16_rne(v.w); l.w = bf16_rne(v.w - bf16f(h.w));
    ((u16x4_t*)hi)[i] = h;
    ((u16x4_t*)lo)[i] = l;
}

// ---------------- splitT: W[K][N] fp32 -> WT hi/lo [N][K] bf16 ----------------
__global__ __launch_bounds__(256)
void splitT_kernel(const float* __restrict__ W, unsigned short* __restrict__ Thi,
                   unsigned short* __restrict__ Tlo, int Kdim, int Ndim)
{
    __shared__ float tile[32][33];
    const int t = threadIdx.x;
    const int kb = blockIdx.y * 32, nb = blockIdx.x * 32;
    const int lr = t >> 3, lc = (t & 7) * 4;
    *(float4*)&tile[lr][lc] = *(const float4*)&W[(size_t)(kb + lr) * Ndim + nb + lc];
    __syncthreads();
    const float v0 = tile[lc + 0][lr];
    const float v1 = tile[lc + 1][lr];
    const float v2 = tile[lc + 2][lr];
    const float v3 = tile[lc + 3][lr];
    u16x4_t h, l;
    h.x = bf16_rne(v0); l.x = bf16_rne(v0 - bf16f(h.x));
    h.y = bf16_rne(v1); l.y = bf16_rne(v1 - bf16f(h.y));
    h.z = bf16_rne(v2); l.z = bf16_rne(v2 - bf16f(h.z));
    h.w = bf16_rne(v3); l.w = bf16_rne(v3 - bf16f(h.w));
    *(u16x4_t*)&Thi[(size_t)(nb + lr) * Kdim + kb + lc] = h;
    *(u16x4_t*)&Tlo[(size_t)(nb + lr) * Kdim + kb + lc] = l;
}

// ---------------- MFMA GEMM, bf16x3.  MODE 0: fp32 C + bias.  MODE 1: QKV split epilogue ----------------
template<int N, int MODE>
__global__ __launch_bounds__(256, 2)
void gemm_mfma_kernel(const unsigned short* __restrict__ Ahi, const unsigned short* __restrict__ Alo,
                      const unsigned short* __restrict__ BThi, const unsigned short* __restrict__ BTlo,
                      const float* __restrict__ bias, float* __restrict__ C,
                      unsigned short* __restrict__ q_hi, unsigned short* __restrict__ q_lo,
                      unsigned short* __restrict__ k_hi, unsigned short* __restrict__ k_lo,
                      unsigned short* __restrict__ v_hi, unsigned short* __restrict__ v_lo)
{
    constexpr int K = 768;
    __shared__ unsigned short As[128 * LS];
    __shared__ unsigned short Bs[128 * LS];
    const int tid = threadIdx.x;
    const int w = tid >> 6, lane = tid & 63, g = lane >> 4, r = lane & 15;
    const int wr = (w >> 1) * 64, wc = (w & 1) * 64;
    const int m0 = blockIdx.y * 128, n0 = blockIdx.x * 128;
    const int srow = tid >> 1, sh = (tid & 1) * 16;

    const unsigned short* aH = Ahi + (size_t)(m0 + srow) * K + sh;
    const unsigned short* aL = Alo + (size_t)(m0 + srow) * K + sh;
    const unsigned short* bH = BThi + (size_t)(n0 + srow) * K + sh;
    const unsigned short* bL = BTlo + (size_t)(n0 + srow) * K + sh;

    f32x4_t acc[4][4];
#pragma unroll
    for (int i = 0; i < 4; ++i)
#pragma unroll
        for (int j = 0; j < 4; ++j)
#pragma unroll
            for (int q = 0; q < 4; ++q) acc[i][j][q] = 0.f;

    for (int k0 = 0; k0 < K; k0 += 32) {
        bf16x8_t va0 = *(const bf16x8_t*)(aH + k0);
        bf16x8_t va1 = *(const bf16x8_t*)(aH + k0 + 8);
        bf16x8_t wa0 = *(const bf16x8_t*)(aL + k0);
        bf16x8_t wa1 = *(const bf16x8_t*)(aL + k0 + 8);
        bf16x8_t vb0 = *(const bf16x8_t*)(bH + k0);
        bf16x8_t vb1 = *(const bf16x8_t*)(bH + k0 + 8);
        bf16x8_t wb0 = *(const bf16x8_t*)(bL + k0);
        bf16x8_t wb1 = *(const bf16x8_t*)(bL + k0 + 8);
        __syncthreads();
        *(bf16x8_t*)&As[srow * LS + sh]          = va0;
        *(bf16x8_t*)&As[srow * LS + sh + 8]      = va1;
        *(bf16x8_t*)&As[srow * LS + 32 + sh]     = wa0;
        *(bf16x8_t*)&As[srow * LS + 32 + sh + 8] = wa1;
        *(bf16x8_t*)&Bs[srow * LS + sh]          = vb0;
        *(bf16x8_t*)&Bs[srow * LS + sh + 8]      = vb1;
        *(bf16x8_t*)&Bs[srow * LS + 32 + sh]     = wb0;
        *(bf16x8_t*)&Bs[srow * LS + 32 + sh + 8] = wb1;
        __syncthreads();
        bf16x8_t amh[4], aml[4];
#pragma unroll
        for (int i = 0; i < 4; ++i) {
            amh[i] = *(const bf16x8_t*)&As[(wr + 16 * i + r) * LS + 8 * g];
            aml[i] = *(const bf16x8_t*)&As[(wr + 16 * i + r) * LS + 32 + 8 * g];
        }
#pragma unroll
        for (int j = 0; j < 4; ++j) {
            bf16x8_t bnh = *(const bf16x8_t*)&Bs[(wc + 16 * j + r) * LS + 8 * g];
            bf16x8_t bnl = *(const bf16x8_t*)&Bs[(wc + 16 * j + r) * LS + 32 + 8 * g];
#pragma unroll
            for (int i = 0; i < 4; ++i) {
                acc[i][j] = __builtin_amdgcn_mfma_f32_16x16x32_bf16(amh[i], bnh, acc[i][j], 0, 0, 0);
                acc[i][j] = __builtin_amdgcn_mfma_f32_16x16x32_bf16(amh[i], bnl, acc[i][j], 0, 0, 0);
                acc[i][j] = __builtin_amdgcn_mfma_f32_16x16x32_bf16(aml[i], bnh, acc[i][j], 0, 0, 0);
            }
        }
    }

    if constexpr (MODE == 0) {
#pragma unroll
        for (int j = 0; j < 4; ++j) {
            const float bj = bias[n0 + wc + 16 * j + r];
#pragma unroll
            for (int i = 0; i < 4; ++i) {
                float* Cp = C + (size_t)(m0 + wr + 16 * i + 4 * g) * N + n0 + wc + 16 * j + r;
#pragma unroll
                for (int q = 0; q < 4; ++q)
                    Cp[(size_t)q * N] = acc[i][j][q] + bj;
            }
        }
    } else {
        const int third = n0 >= 1536 ? 2 : (n0 >= 768 ? 1 : 0);   // uniform per block (128 divides 768)
        unsigned short* outH = third == 2 ? v_hi : third == 1 ? k_hi : q_hi;
        unsigned short* outL = third == 2 ? v_lo : third == 1 ? k_lo : q_lo;
#pragma unroll
        for (int j = 0; j < 4; ++j) {
            const int n = n0 + wc + 16 * j + r;
            const float bj = bias[n];
            const int nn = n - third * 768;
            const int h = nn >> 6, d = nn & 63;
#pragma unroll
            for (int i = 0; i < 4; ++i) {
                const int m = m0 + wr + 16 * i + 4 * g;
                const int b = m >> 10, t = m & 1023;
                const size_t hb = ((size_t)(b * NH + h)) << 16;
                unsigned short* dh = outH + hb + (size_t)t * 64 + d;
                unsigned short* dl = outL + hb + (size_t)t * 64 + d;
#pragma unroll
                for (int q = 0; q < 4; ++q) {
                    const float v = acc[i][j][q] + bj;
                    const unsigned short hvv = bf16_rne(v);
                    dh[(size_t)q * 64] = hvv;
                    dl[(size_t)q * 64] = bf16_rne(v - bf16f(hvv));
                }
            }
        }
    }
}

// ------------- rel-pos bias tables v2: one block per (qc, bh), both tables -------------
__global__ __launch_bounds__(256)
void relbias2_kernel(const unsigned short* __restrict__ qhi, const unsigned short* __restrict__ qlo,
                     const float* __restrict__ rel_h, const float* __restrict__ rel_w,
                     float* __restrict__ biasH, float* __restrict__ biasW)
{
    __shared__ float qs[32 * 68];
    const int tid = threadIdx.x;
    const int qc = blockIdx.x;     // 0..31 (H index of q row-group)
    const int bh = blockIdx.y;     // 0..95
    const size_t hb = (size_t)bh << 16;
    {
        const int i = tid >> 3, p8 = (tid & 7) * 8;
        const bf16x8_t hv = *(const bf16x8_t*)(qhi + hb + (size_t)(qc * 32 + i) * 64 + p8);
        const bf16x8_t lv = *(const bf16x8_t*)(qlo + hb + (size_t)(qc * 32 + i) * 64 + p8);
        float* dst = &qs[i * 68 + p8];
#pragma unroll
        for (int e = 0; e < 8; ++e)
            dst[e] = bf16f((unsigned short)hv[e]) + bf16f((unsigned short)lv[e]);
    }
    __syncthreads();
    const int i = tid >> 3, kg = tid & 7;     // i = w index within row-group
    const float* qrow = &qs[i * 68];
    const size_t orow = ((size_t)bh << 15) + (size_t)(qc * 32 + i) * 32;
#pragma unroll
    for (int jj = 0; jj < 4; ++jj) {
        const int kc = kg + 8 * jj;
        const float* rh = rel_h + (qc - kc + 31) * 64;
        const float* rw = rel_w + (i - kc + 31) * 64;
        float ah = 0.f, aw = 0.f;
#pragma unroll
        for (int d = 0; d < 64; d += 4) {
            const float4 qv = *(const float4*)(qrow + d);
            const float4 rhv = *(const float4*)(rh + d);
            const float4 rwv = *(const float4*)(rw + d);
            ah = fmaf(qv.x, rhv.x, ah); aw = fmaf(qv.x, rwv.x, aw);
            ah = fmaf(qv.y, rhv.y, ah); aw = fmaf(qv.y, rwv.y, aw);
            ah = fmaf(qv.z, rhv.z, ah); aw = fmaf(qv.z, rwv.z, aw);
            ah = fmaf(qv.w, rhv.w, ah); aw = fmaf(qv.w, rwv.w, aw);
        }
        biasH[orow + kc] = ah;
        biasW[orow + kc] = aw;
    }
}

// ------------- MFMA flash attention v2: pre-split bf16 inputs, 3 blocks/CU -------------
__global__ __launch_bounds__(256, 3)
void attn2_kernel(const unsigned short* __restrict__ qhi, const unsigned short* __restrict__ qlo,
                  const unsigned short* __restrict__ khi, const unsigned short* __restrict__ klo,
                  const unsigned short* __restrict__ vhi, const unsigned short* __restrict__ vlo,
                  const float* __restrict__ biasH, const float* __restrict__ biasW,
                  unsigned short* __restrict__ outh, unsigned short* __restrict__ outl)
{
    __shared__ unsigned short ksh[64 * LS], ksl[64 * LS];
    __shared__ unsigned short vsh[64 * LS], vsl[64 * LS];   // V transposed [d][t]
    __shared__ unsigned short psh[64 * 64], psl[64 * 64];   // XOR-swizzled 16B chunks

    const int tid  = threadIdx.x;
    const int bh   = blockIdx.y;
    const int s0   = blockIdx.x * 64;
    const int w    = tid >> 6;
    const int lane = tid & 63;
    const int g    = lane >> 4;
    const int r    = lane & 15;
    const size_t hb = (size_t)bh << 16;

    // ---- stage Q into ksh/ksl temporarily, pull fragments to registers ----
    {
        const int row = tid >> 2, c16 = (tid & 3) * 16;
        const unsigned short* qh = qhi + hb + (size_t)(s0 + row) * 64 + c16;
        const unsigned short* ql = qlo + hb + (size_t)(s0 + row) * 64 + c16;
        const bf16x8_t a0 = *(const bf16x8_t*)qh;
        const bf16x8_t a1 = *(const bf16x8_t*)(qh + 8);
        const bf16x8_t b0 = *(const bf16x8_t*)ql;
        const bf16x8_t b1 = *(const bf16x8_t*)(ql + 8);
        *(bf16x8_t*)&ksh[row * LS + c16]     = a0;
        *(bf16x8_t*)&ksh[row * LS + c16 + 8] = a1;
        *(bf16x8_t*)&ksl[row * LS + c16]     = b0;
        *(bf16x8_t*)&ksl[row * LS + c16 + 8] = b1;
    }
    __syncthreads();
    bf16x8_t aqh[2], aql[2];
#pragma unroll
    for (int c = 0; c < 2; ++c) {
        aqh[c] = *(const bf16x8_t*)&ksh[(w * 16 + r) * LS + c * 32 + 8 * g];
        aql[c] = *(const bf16x8_t*)&ksl[(w * 16 + r) * LS + c * 32 + 8 * g];
    }
    float bw[4][2];
#pragma unroll
    for (int reg = 0; reg < 4; ++reg)
#pragma unroll
        for (int j = 0; j < 2; ++j)
            bw[reg][j] = biasW[((size_t)bh << 15) + (size_t)(s0 + w * 16 + 4 * g + reg) * 32 + 16 * j + r];
    __syncthreads();

    f32x4_t oacc[4];
    float mrun[4], lrun[4];
#pragma unroll
    for (int i = 0; i < 4; ++i) {
        mrun[i] = -1e30f; lrun[i] = 0.f;
#pragma unroll
        for (int j = 0; j < 4; ++j) oacc[i][j] = 0.f;
    }

    const int krow = tid >> 2, kc16 = (tid & 3) * 16;   // K staging map
    const int tb = (tid >> 4) * 4, d0 = (tid & 15) * 4; // V staging map
    const float* bhrow = biasH + ((size_t)bh << 15) + (size_t)(s0 + w * 16) * 32;

    for (int t0 = 0; t0 < SEQ; t0 += 64) {
        // ---- stage K tile ----
        {
            const unsigned short* kh = khi + hb + (size_t)(t0 + krow) * 64 + kc16;
            const unsigned short* kl = klo + hb + (size_t)(t0 + krow) * 64 + kc16;
            const bf16x8_t a0 = *(const bf16x8_t*)kh;
            const bf16x8_t a1 = *(const bf16x8_t*)(kh + 8);
            const bf16x8_t b0 = *(const bf16x8_t*)kl;
            const bf16x8_t b1 = *(const bf16x8_t*)(kl + 8);
            *(bf16x8_t*)&ksh[krow * LS + kc16]     = a0;
            *(bf16x8_t*)&ksh[krow * LS + kc16 + 8] = a1;
            *(bf16x8_t*)&ksl[krow * LS + kc16]     = b0;
            *(bf16x8_t*)&ksl[krow * LS + kc16 + 8] = b1;
        }
        // ---- stage V transposed (register 4x4 repack, no conversion) ----
        {
            u16x4_t rh[4], rl[4];
#pragma unroll
            for (int i = 0; i < 4; ++i) {
                rh[i] = *(const u16x4_t*)(vhi + hb + (size_t)(t0 + tb + i) * 64 + d0);
                rl[i] = *(const u16x4_t*)(vlo + hb + (size_t)(t0 + tb + i) * 64 + d0);
            }
#pragma unroll
            for (int c2 = 0; c2 < 4; ++c2) {
                u16x4_t th, tl;
                th.x = rh[0][c2]; th.y = rh[1][c2]; th.z = rh[2][c2]; th.w = rh[3][c2];
                tl.x = rl[0][c2]; tl.y = rl[1][c2]; tl.z = rl[2][c2]; tl.w = rl[3][c2];
                *(u16x4_t*)&vsh[(d0 + c2) * LS + tb] = th;
                *(u16x4_t*)&vsl[(d0 + c2) * LS + tb] = tl;
            }
        }
        __syncthreads();

        // ---- QK^T (bf16x3) ----
        f32x4_t sacc[4];
#pragma unroll
        for (int fj = 0; fj < 4; ++fj)
#pragma unroll
            for (int j = 0; j < 4; ++j) sacc[fj][j] = 0.f;
#pragma unroll
        for (int c = 0; c < 2; ++c)
#pragma unroll
            for (int fj = 0; fj < 4; ++fj) {
                const bf16x8_t bkh = *(const bf16x8_t*)&ksh[(16 * fj + r) * LS + c * 32 + 8 * g];
                const bf16x8_t bkl = *(const bf16x8_t*)&ksl[(16 * fj + r) * LS + c * 32 + 8 * g];
                sacc[fj] = __builtin_amdgcn_mfma_f32_16x16x32_bf16(aqh[c], bkh, sacc[fj], 0, 0, 0);
                sacc[fj] = __builtin_amdgcn_mfma_f32_16x16x32_bf16(aqh[c], bkl, sacc[fj], 0, 0, 0);
                sacc[fj] = __builtin_amdgcn_mfma_f32_16x16x32_bf16(aql[c], bkh, sacc[fj], 0, 0, 0);
            }

        // ---- logits = qk*0.125 + biasH + biasW ----
        const int kh0 = t0 >> 5;
        float bh0[4], bh1[4];
#pragma unroll
        for (int reg = 0; reg < 4; ++reg) {
            bh0[reg] = bhrow[(4 * g + reg) * 32 + kh0];
            bh1[reg] = bhrow[(4 * g + reg) * 32 + kh0 + 1];
        }
#pragma unroll
        for (int fj = 0; fj < 4; ++fj)
#pragma unroll
            for (int reg = 0; reg < 4; ++reg)
                sacc[fj][reg] = fmaf(sacc[fj][reg], 0.125f,
                                     ((fj >> 1) ? bh1[reg] : bh0[reg]) + bw[reg][fj & 1]);

        // ---- online softmax ----
#pragma unroll
        for (int reg = 0; reg < 4; ++reg) {
            float tm = fmaxf(fmaxf(sacc[0][reg], sacc[1][reg]),
                             fmaxf(sacc[2][reg], sacc[3][reg]));
#pragma unroll
            for (int off = 1; off < 16; off <<= 1) tm = fmaxf(tm, __shfl_xor(tm, off));
            const float mn = fmaxf(mrun[reg], tm);
            const float sc = __expf(mrun[reg] - mn);
            mrun[reg] = mn;
            float rs = 0.f;
#pragma unroll
            for (int fj = 0; fj < 4; ++fj) {
                const float e = __expf(sacc[fj][reg] - mn);
                sacc[fj][reg] = e;
                rs += e;
            }
#pragma unroll
            for (int off = 1; off < 16; off <<= 1) rs += __shfl_xor(rs, off);
            lrun[reg] = lrun[reg] * sc + rs;
#pragma unroll
            for (int fd = 0; fd < 4; ++fd) oacc[fd][reg] *= sc;
        }

        // ---- store P hi/lo, XOR-swizzled 16B chunks (wave-private rows) ----
#pragma unroll
        for (int fj = 0; fj < 4; ++fj)
#pragma unroll
            for (int reg = 0; reg < 4; ++reg) {
                const float e = sacc[fj][reg];
                const unsigned short ph = bf16_rne(e);
                const unsigned short pl = bf16_rne(e - bf16f(ph));
                const int row = w * 16 + 4 * g + reg;
                const int addr = row * 64 + (((2 * fj + (r >> 3)) ^ (row & 7)) << 3) + (r & 7);
                psh[addr] = ph;
                psl[addr] = pl;
            }
        asm volatile("s_waitcnt lgkmcnt(0)" ::: "memory");
        __builtin_amdgcn_sched_barrier(0);

        // ---- PV (bf16x3) ----
#pragma unroll
        for (int c = 0; c < 2; ++c) {
            const int prow = w * 16 + r;
            const int paddr = prow * 64 + (((4 * c + g) ^ (prow & 7)) << 3);
            const bf16x8_t aph = *(const bf16x8_t*)&psh[paddr];
            const bf16x8_t apl = *(const bf16x8_t*)&psl[paddr];
#pragma unroll
            for (int fd = 0; fd < 4; ++fd) {
                const bf16x8_t bvh = *(const bf16x8_t*)&vsh[(16 * fd + r) * LS + c * 32 + 8 * g];
                const bf16x8_t bvl = *(const bf16x8_t*)&vsl[(16 * fd + r) * LS + c * 32 + 8 * g];
                oacc[fd] = __builtin_amdgcn_mfma_f32_16x16x32_bf16(aph, bvh, oacc[fd], 0, 0, 0);
                oacc[fd] = __builtin_amdgcn_mfma_f32_16x16x32_bf16(aph, bvl, oacc[fd], 0, 0, 0);
                oacc[fd] = __builtin_amdgcn_mfma_f32_16x16x32_bf16(apl, bvh, oacc[fd], 0, 0, 0);
            }
        }
        __syncthreads();
    }

    // ---- epilogue: normalize + split-store ----
    const int b = bh / NH, h = bh - (bh / NH) * NH;
#pragma unroll
    for (int reg = 0; reg < 4; ++reg) {
        const float rinv = 1.f / lrun[reg];
        const int qrow = s0 + w * 16 + 4 * g + reg;
        unsigned short* oph = outh + ((size_t)b * SEQ + qrow) * C_ + h * HDIM;
        unsigned short* opl = outl + ((size_t)b * SEQ + qrow) * C_ + h * HDIM;
#pragma unroll
        for (int fd = 0; fd < 4; ++fd) {
            const float v = oacc[fd][reg] * rinv;
            const unsigned short hv = bf16_rne(v);
            oph[16 * fd + r] = hv;
            opl[16 * fd + r] = bf16_rne(v - bf16f(hv));
        }
    }
}

extern "C" void kernel_launch(void* const* d_in, const int* in_sizes, int n_in,
                              void* d_out, int out_size, void* d_ws, size_t ws_size,
                              hipStream_t stream) {
    (void)in_sizes; (void)n_in; (void)out_size; (void)ws_size;
    const float* x      = (const float*)d_in[0];
    const float* w_qkv  = (const float*)d_in[1];
    const float* b_qkv  = (const float*)d_in[2];
    const float* w_proj = (const float*)d_in[3];
    const float* b_proj = (const float*)d_in[4];
    const float* rel_h  = (const float*)d_in[5];
    const float* rel_w  = (const float*)d_in[6];
    float* out = (float*)d_out;

    char* base = (char*)d_ws;
    unsigned short* xhi   = (unsigned short*)(base + 0);          // 12,582,912 B
    unsigned short* xlo   = (unsigned short*)(base + 12582912);
    unsigned short* wqh   = (unsigned short*)(base + 25165824);   //  3,538,944 B
    unsigned short* wql   = (unsigned short*)(base + 28704768);
    unsigned short* wph   = (unsigned short*)(base + 32243712);   //  1,179,648 B
    unsigned short* wpl   = (unsigned short*)(base + 33423360);
    unsigned short* qhi   = (unsigned short*)(base + 34603008);   // 12,582,912 B each
    unsigned short* qlo   = (unsigned short*)(base + 47185920);
    unsigned short* khi   = (unsigned short*)(base + 59768832);
    unsigned short* klo   = (unsigned short*)(base + 72351744);
    unsigned short* vhi   = (unsigned short*)(base + 84934656);
    unsigned short* vlo   = (unsigned short*)(base + 97517568);
    float*          biasH = (float*)(base + 110100480);           // 12,582,912 B
    float*          biasW = (float*)(base + 122683392);
    unsigned short* ohif  = xhi;   // x splits dead after QKV GEMM
    unsigned short* olo   = xlo;

    // 1. split x -> hi/lo
    split_kernel<<<6144, 256, 0, stream>>>(x, xhi, xlo);
    // 2. transpose+split weights
    {
        dim3 gq(C3 / 32, C_ / 32);
        splitT_kernel<<<gq, 256, 0, stream>>>(w_qkv, wqh, wql, C_, C3);
        dim3 gp(C_ / 32, C_ / 32);
        splitT_kernel<<<gp, 256, 0, stream>>>(w_proj, wph, wpl, C_, C_);
    }
    // 3. QKV GEMM with split epilogue -> q/k/v hi/lo [bh][t][64]
    {
        dim3 grid(C3 / 128, 8192 / 128);
        gemm_mfma_kernel<C3, 1><<<grid, 256, 0, stream>>>(xhi, xlo, wqh, wql, b_qkv, nullptr,
                                                          qhi, qlo, khi, klo, vhi, vlo);
    }
    // 4. rel-pos bias tables (both in one kernel)
    {
        dim3 grid(32, 96);
        relbias2_kernel<<<grid, 256, 0, stream>>>(qhi, qlo, rel_h, rel_w, biasH, biasW);
    }
    // 5. MFMA flash attention
    {
        dim3 grid(SEQ / 64, 96);
        attn2_kernel<<<grid, 256, 0, stream>>>(qhi, qlo, khi, klo, vhi, vlo, biasH, biasW, ohif, olo);
    }
    // 6. out = attnout @ w_proj + b_proj
    {
        dim3 grid(C_ / 128, 8192 / 128);
        gemm_mfma_kernel<C_, 0><<<grid, 256, 0, stream>>>(ohif, olo, wph, wpl, b_proj, out,
                                                          nullptr, nullptr, nullptr, nullptr, nullptr, nullptr);
    }
}

// Round 7
// 529.811 us; speedup vs baseline: 2.4358x; 1.0134x over previous
//
#include <hip/hip_runtime.h>
#include <cstdint>
#include <cstddef>

#define NH 12
#define HDIM 64
#define C_ 768
#define C3 2304
#define SEQ 1024
#define LS 72    // LDS row stride in bf16 elems (144B, 16B-aligned)

typedef short bf16x8_t __attribute__((ext_vector_type(8)));
typedef float f32x4_t __attribute__((ext_vector_type(4)));
typedef unsigned short u16x4_t __attribute__((ext_vector_type(4)));

__device__ __forceinline__ unsigned short bf16_rne(float x) {
    unsigned int u = __float_as_uint(x);
    u += 0x7FFFu + ((u >> 16) & 1u);
    return (unsigned short)(u >> 16);
}
__device__ __forceinline__ float bf16f(unsigned short h) {
    return __uint_as_float(((unsigned int)h) << 16);
}

// ---------------- split: fp32 -> hi/lo bf16 (elementwise) ----------------
__global__ __launch_bounds__(256)
void split_kernel(const float* __restrict__ in, unsigned short* __restrict__ hi,
                  unsigned short* __restrict__ lo)
{
    const int i = blockIdx.x * 256 + threadIdx.x;
    float4 v = ((const float4*)in)[i];
    u16x4_t h, l;
    h.x = bf16_rne(v.x); l.x = bf16_rne(v.x - bf16f(h.x));
    h.y = bf16_rne(v.y); l.y = bf16_rne(v.y - bf16f(h.y));
    h.z = bf16_rne(v.z); l.z = bf16_rne(v.z - bf16f(h.z));
    h.w = bf16_rne(v.w); l.w = bf16_rne(v.w - bf16f(h.w));
    ((u16x4_t*)hi)[i] = h;
    ((u16x4_t*)lo)[i] = l;
}

// ---------------- splitT: W[K][N] fp32 -> WT hi/lo [N][K] bf16 ----------------
__global__ __launch_bounds__(256)
void splitT_kernel(const float* __restrict__ W, unsigned short* __restrict__ Thi,
                   unsigned short* __restrict__ Tlo, int Kdim, int Ndim)
{
    __shared__ float tile[32][33];
    const int t = threadIdx.x;
    const int kb = blockIdx.y * 32, nb = blockIdx.x * 32;
    const int lr = t >> 3, lc = (t & 7) * 4;
    *(float4*)&tile[lr][lc] = *(const float4*)&W[(size_t)(kb + lr) * Ndim + nb + lc];
    __syncthreads();
    const float v0 = tile[lc + 0][lr];
    const float v1 = tile[lc + 1][lr];
    const float v2 = tile[lc + 2][lr];
    const float v3 = tile[lc + 3][lr];
    u16x4_t h, l;
    h.x = bf16_rne(v0); l.x = bf16_rne(v0 - bf16f(h.x));
    h.y = bf16_rne(v1); l.y = bf16_rne(v1 - bf16f(h.y));
    h.z = bf16_rne(v2); l.z = bf16_rne(v2 - bf16f(h.z));
    h.w = bf16_rne(v3); l.w = bf16_rne(v3 - bf16f(h.w));
    *(u16x4_t*)&Thi[(size_t)(nb + lr) * Kdim + kb + lc] = h;
    *(u16x4_t*)&Tlo[(size_t)(nb + lr) * Kdim + kb + lc] = l;
}

// ---------------- MFMA GEMM, bf16x3.  MODE 0: fp32 C + bias.  MODE 1: QKV bf16 epilogue ----------------
template<int N, int MODE>
__global__ __launch_bounds__(256, 2)
void gemm_mfma_kernel(const unsigned short* __restrict__ Ahi, const unsigned short* __restrict__ Alo,
                      const unsigned short* __restrict__ BThi, const unsigned short* __restrict__ BTlo,
                      const float* __restrict__ bias, float* __restrict__ C,
                      unsigned short* __restrict__ q_hi, unsigned short* __restrict__ k_hi,
                      unsigned short* __restrict__ v_hi)
{
    constexpr int K = 768;
    __shared__ unsigned short As[128 * LS];
    __shared__ unsigned short Bs[128 * LS];
    const int tid = threadIdx.x;
    const int w = tid >> 6, lane = tid & 63, g = lane >> 4, r = lane & 15;
    const int wr = (w >> 1) * 64, wc = (w & 1) * 64;
    const int m0 = blockIdx.y * 128, n0 = blockIdx.x * 128;
    const int srow = tid >> 1, sh = (tid & 1) * 16;

    const unsigned short* aH = Ahi + (size_t)(m0 + srow) * K + sh;
    const unsigned short* aL = Alo + (size_t)(m0 + srow) * K + sh;
    const unsigned short* bH = BThi + (size_t)(n0 + srow) * K + sh;
    const unsigned short* bL = BTlo + (size_t)(n0 + srow) * K + sh;

    f32x4_t acc[4][4];
#pragma unroll
    for (int i = 0; i < 4; ++i)
#pragma unroll
        for (int j = 0; j < 4; ++j)
#pragma unroll
            for (int q = 0; q < 4; ++q) acc[i][j][q] = 0.f;

    for (int k0 = 0; k0 < K; k0 += 32) {
        bf16x8_t va0 = *(const bf16x8_t*)(aH + k0);
        bf16x8_t va1 = *(const bf16x8_t*)(aH + k0 + 8);
        bf16x8_t wa0 = *(const bf16x8_t*)(aL + k0);
        bf16x8_t wa1 = *(const bf16x8_t*)(aL + k0 + 8);
        bf16x8_t vb0 = *(const bf16x8_t*)(bH + k0);
        bf16x8_t vb1 = *(const bf16x8_t*)(bH + k0 + 8);
        bf16x8_t wb0 = *(const bf16x8_t*)(bL + k0);
        bf16x8_t wb1 = *(const bf16x8_t*)(bL + k0 + 8);
        __syncthreads();
        *(bf16x8_t*)&As[srow * LS + sh]          = va0;
        *(bf16x8_t*)&As[srow * LS + sh + 8]      = va1;
        *(bf16x8_t*)&As[srow * LS + 32 + sh]     = wa0;
        *(bf16x8_t*)&As[srow * LS + 32 + sh + 8] = wa1;
        *(bf16x8_t*)&Bs[srow * LS + sh]          = vb0;
        *(bf16x8_t*)&Bs[srow * LS + sh + 8]      = vb1;
        *(bf16x8_t*)&Bs[srow * LS + 32 + sh]     = wb0;
        *(bf16x8_t*)&Bs[srow * LS + 32 + sh + 8] = wb1;
        __syncthreads();
        bf16x8_t amh[4], aml[4];
#pragma unroll
        for (int i = 0; i < 4; ++i) {
            amh[i] = *(const bf16x8_t*)&As[(wr + 16 * i + r) * LS + 8 * g];
            aml[i] = *(const bf16x8_t*)&As[(wr + 16 * i + r) * LS + 32 + 8 * g];
        }
#pragma unroll
        for (int j = 0; j < 4; ++j) {
            bf16x8_t bnh = *(const bf16x8_t*)&Bs[(wc + 16 * j + r) * LS + 8 * g];
            bf16x8_t bnl = *(const bf16x8_t*)&Bs[(wc + 16 * j + r) * LS + 32 + 8 * g];
#pragma unroll
            for (int i = 0; i < 4; ++i) {
                acc[i][j] = __builtin_amdgcn_mfma_f32_16x16x32_bf16(amh[i], bnh, acc[i][j], 0, 0, 0);
                acc[i][j] = __builtin_amdgcn_mfma_f32_16x16x32_bf16(amh[i], bnl, acc[i][j], 0, 0, 0);
                acc[i][j] = __builtin_amdgcn_mfma_f32_16x16x32_bf16(aml[i], bnh, acc[i][j], 0, 0, 0);
            }
        }
    }

    if constexpr (MODE == 0) {
#pragma unroll
        for (int j = 0; j < 4; ++j) {
            const float bj = bias[n0 + wc + 16 * j + r];
#pragma unroll
            for (int i = 0; i < 4; ++i) {
                float* Cp = C + (size_t)(m0 + wr + 16 * i + 4 * g) * N + n0 + wc + 16 * j + r;
#pragma unroll
                for (int q = 0; q < 4; ++q)
                    Cp[(size_t)q * N] = acc[i][j][q] + bj;
            }
        }
    } else {
        const int third = n0 >= 1536 ? 2 : (n0 >= 768 ? 1 : 0);   // uniform per block (128 divides 768)
        unsigned short* outH = third == 2 ? v_hi : third == 1 ? k_hi : q_hi;
#pragma unroll
        for (int j = 0; j < 4; ++j) {
            const int n = n0 + wc + 16 * j + r;
            const float bj = bias[n];
            const int nn = n - third * 768;
            const int h = nn >> 6, d = nn & 63;
#pragma unroll
            for (int i = 0; i < 4; ++i) {
                const int m = m0 + wr + 16 * i + 4 * g;
                const int b = m >> 10, t = m & 1023;
                const size_t hb = ((size_t)(b * NH + h)) << 16;
                unsigned short* dh = outH + hb + (size_t)t * 64 + d;
#pragma unroll
                for (int q = 0; q < 4; ++q)
                    dh[(size_t)q * 64] = bf16_rne(acc[i][j][q] + bj);
            }
        }
    }
}

// ------------- rel-pos bias tables: one block per (qc, bh), both tables, bf16 q -------------
__global__ __launch_bounds__(256)
void relbias2_kernel(const unsigned short* __restrict__ qhi,
                     const float* __restrict__ rel_h, const float* __restrict__ rel_w,
                     float* __restrict__ biasH, float* __restrict__ biasW)
{
    __shared__ float qs[32 * 68];
    const int tid = threadIdx.x;
    const int qc = blockIdx.x;     // 0..31 (H index of q row-group)
    const int bh = blockIdx.y;     // 0..95
    const size_t hb = (size_t)bh << 16;
    {
        const int i = tid >> 3, p8 = (tid & 7) * 8;
        const bf16x8_t hv = *(const bf16x8_t*)(qhi + hb + (size_t)(qc * 32 + i) * 64 + p8);
        float* dst = &qs[i * 68 + p8];
#pragma unroll
        for (int e = 0; e < 8; ++e)
            dst[e] = bf16f((unsigned short)hv[e]);
    }
    __syncthreads();
    const int i = tid >> 3, kg = tid & 7;     // i = w index within row-group
    const float* qrow = &qs[i * 68];
    const size_t orow = ((size_t)bh << 15) + (size_t)(qc * 32 + i) * 32;
#pragma unroll
    for (int jj = 0; jj < 4; ++jj) {
        const int kc = kg + 8 * jj;
        const float* rh = rel_h + (qc - kc + 31) * 64;
        const float* rw = rel_w + (i - kc + 31) * 64;
        float ah = 0.f, aw = 0.f;
#pragma unroll
        for (int d = 0; d < 64; d += 4) {
            const float4 qv = *(const float4*)(qrow + d);
            const float4 rhv = *(const float4*)(rh + d);
            const float4 rwv = *(const float4*)(rw + d);
            ah = fmaf(qv.x, rhv.x, ah); aw = fmaf(qv.x, rwv.x, aw);
            ah = fmaf(qv.y, rhv.y, ah); aw = fmaf(qv.y, rwv.y, aw);
            ah = fmaf(qv.z, rhv.z, ah); aw = fmaf(qv.z, rwv.z, aw);
            ah = fmaf(qv.w, rhv.w, ah); aw = fmaf(qv.w, rwv.w, aw);
        }
        biasH[orow + kc] = ah;
        biasW[orow + kc] = aw;
    }
}

// ------------- MFMA flash attention v3: plain bf16, 5 blocks/CU -------------
// grid (96 heads, 16 q-blocks): consecutive blockIdx.x = heads -> each head pinned to one XCD.
__global__ __launch_bounds__(256, 5)
void attn3_kernel(const unsigned short* __restrict__ qhi,
                  const unsigned short* __restrict__ khi,
                  const unsigned short* __restrict__ vhi,
                  const float* __restrict__ biasH, const float* __restrict__ biasW,
                  unsigned short* __restrict__ outh, unsigned short* __restrict__ outl)
{
    __shared__ unsigned short ksh[64 * LS];
    __shared__ unsigned short vsh[64 * LS];   // V transposed [d][t]
    __shared__ unsigned short psh[64 * 64];   // XOR-swizzled 16B chunks

    const int tid  = threadIdx.x;
    const int bh   = blockIdx.x;
    const int s0   = blockIdx.y * 64;
    const int w    = tid >> 6;
    const int lane = tid & 63;
    const int g    = lane >> 4;
    const int r    = lane & 15;
    const size_t hb = (size_t)bh << 16;

    // ---- Q fragments direct from global (A-frag: row = r, k = c*32 + 8g + j) ----
    bf16x8_t aq[2];
#pragma unroll
    for (int c = 0; c < 2; ++c)
        aq[c] = *(const bf16x8_t*)(qhi + hb + (size_t)(s0 + w * 16 + r) * 64 + c * 32 + 8 * g);
    float bw[4][2];
#pragma unroll
    for (int reg = 0; reg < 4; ++reg)
#pragma unroll
        for (int j = 0; j < 2; ++j)
            bw[reg][j] = biasW[((size_t)bh << 15) + (size_t)(s0 + w * 16 + 4 * g + reg) * 32 + 16 * j + r];

    f32x4_t oacc[4];
    float mrun[4], lrun[4];
#pragma unroll
    for (int i = 0; i < 4; ++i) {
        mrun[i] = -1e30f; lrun[i] = 0.f;
#pragma unroll
        for (int j = 0; j < 4; ++j) oacc[i][j] = 0.f;
    }

    const int krow = tid >> 2, kc16 = (tid & 3) * 16;   // K staging map
    const int tb = (tid >> 4) * 4, d0 = (tid & 15) * 4; // V staging map
    const float* bhrow = biasH + ((size_t)bh << 15) + (size_t)(s0 + w * 16) * 32;

    for (int t0 = 0; t0 < SEQ; t0 += 64) {
        // ---- stage K tile ----
        {
            const unsigned short* kh = khi + hb + (size_t)(t0 + krow) * 64 + kc16;
            const bf16x8_t a0 = *(const bf16x8_t*)kh;
            const bf16x8_t a1 = *(const bf16x8_t*)(kh + 8);
            *(bf16x8_t*)&ksh[krow * LS + kc16]     = a0;
            *(bf16x8_t*)&ksh[krow * LS + kc16 + 8] = a1;
        }
        // ---- stage V transposed (register 4x4 repack) ----
        {
            u16x4_t rv[4];
#pragma unroll
            for (int i = 0; i < 4; ++i)
                rv[i] = *(const u16x4_t*)(vhi + hb + (size_t)(t0 + tb + i) * 64 + d0);
#pragma unroll
            for (int c2 = 0; c2 < 4; ++c2) {
                u16x4_t th;
                th.x = rv[0][c2]; th.y = rv[1][c2]; th.z = rv[2][c2]; th.w = rv[3][c2];
                *(u16x4_t*)&vsh[(d0 + c2) * LS + tb] = th;
            }
        }
        __syncthreads();

        // ---- QK^T (plain bf16) ----
        f32x4_t sacc[4];
#pragma unroll
        for (int fj = 0; fj < 4; ++fj)
#pragma unroll
            for (int j = 0; j < 4; ++j) sacc[fj][j] = 0.f;
#pragma unroll
        for (int c = 0; c < 2; ++c)
#pragma unroll
            for (int fj = 0; fj < 4; ++fj) {
                const bf16x8_t bkh = *(const bf16x8_t*)&ksh[(16 * fj + r) * LS + c * 32 + 8 * g];
                sacc[fj] = __builtin_amdgcn_mfma_f32_16x16x32_bf16(aq[c], bkh, sacc[fj], 0, 0, 0);
            }

        // ---- logits = qk*0.125 + biasH + biasW ----
        const int kh0 = t0 >> 5;
        float bh0[4], bh1[4];
#pragma unroll
        for (int reg = 0; reg < 4; ++reg) {
            bh0[reg] = bhrow[(4 * g + reg) * 32 + kh0];
            bh1[reg] = bhrow[(4 * g + reg) * 32 + kh0 + 1];
        }
#pragma unroll
        for (int fj = 0; fj < 4; ++fj)
#pragma unroll
            for (int reg = 0; reg < 4; ++reg)
                sacc[fj][reg] = fmaf(sacc[fj][reg], 0.125f,
                                     ((fj >> 1) ? bh1[reg] : bh0[reg]) + bw[reg][fj & 1]);

        // ---- online softmax ----
#pragma unroll
        for (int reg = 0; reg < 4; ++reg) {
            float tm = fmaxf(fmaxf(sacc[0][reg], sacc[1][reg]),
                             fmaxf(sacc[2][reg], sacc[3][reg]));
#pragma unroll
            for (int off = 1; off < 16; off <<= 1) tm = fmaxf(tm, __shfl_xor(tm, off));
            const float mn = fmaxf(mrun[reg], tm);
            const float sc = __expf(mrun[reg] - mn);
            mrun[reg] = mn;
            float rs = 0.f;
#pragma unroll
            for (int fj = 0; fj < 4; ++fj) {
                const float e = __expf(sacc[fj][reg] - mn);
                sacc[fj][reg] = e;
                rs += e;
            }
#pragma unroll
            for (int off = 1; off < 16; off <<= 1) rs += __shfl_xor(rs, off);
            lrun[reg] = lrun[reg] * sc + rs;
#pragma unroll
            for (int fd = 0; fd < 4; ++fd) oacc[fd][reg] *= sc;
        }

        // ---- store P, XOR-swizzled 16B chunks (wave-private rows) ----
#pragma unroll
        for (int fj = 0; fj < 4; ++fj)
#pragma unroll
            for (int reg = 0; reg < 4; ++reg) {
                const int row = w * 16 + 4 * g + reg;
                const int addr = row * 64 + (((2 * fj + (r >> 3)) ^ (row & 7)) << 3) + (r & 7);
                psh[addr] = bf16_rne(sacc[fj][reg]);
            }
        asm volatile("s_waitcnt lgkmcnt(0)" ::: "memory");
        __builtin_amdgcn_sched_barrier(0);

        // ---- PV (plain bf16) ----
#pragma unroll
        for (int c = 0; c < 2; ++c) {
            const int prow = w * 16 + r;
            const int paddr = prow * 64 + (((4 * c + g) ^ (prow & 7)) << 3);
            const bf16x8_t aph = *(const bf16x8_t*)&psh[paddr];
#pragma unroll
            for (int fd = 0; fd < 4; ++fd) {
                const bf16x8_t bvh = *(const bf16x8_t*)&vsh[(16 * fd + r) * LS + c * 32 + 8 * g];
                oacc[fd] = __builtin_amdgcn_mfma_f32_16x16x32_bf16(aph, bvh, oacc[fd], 0, 0, 0);
            }
        }
        __syncthreads();
    }

    // ---- epilogue: normalize + split-store (hi/lo feeds the bf16x3 proj GEMM) ----
    const int b = bh / NH, h = bh - (bh / NH) * NH;
#pragma unroll
    for (int reg = 0; reg < 4; ++reg) {
        const float rinv = 1.f / lrun[reg];
        const int qrow = s0 + w * 16 + 4 * g + reg;
        unsigned short* oph = outh + ((size_t)b * SEQ + qrow) * C_ + h * HDIM;
        unsigned short* opl = outl + ((size_t)b * SEQ + qrow) * C_ + h * HDIM;
#pragma unroll
        for (int fd = 0; fd < 4; ++fd) {
            const float v = oacc[fd][reg] * rinv;
            const unsigned short hv = bf16_rne(v);
            oph[16 * fd + r] = hv;
            opl[16 * fd + r] = bf16_rne(v - bf16f(hv));
        }
    }
}

extern "C" void kernel_launch(void* const* d_in, const int* in_sizes, int n_in,
                              void* d_out, int out_size, void* d_ws, size_t ws_size,
                              hipStream_t stream) {
    (void)in_sizes; (void)n_in; (void)out_size; (void)ws_size;
    const float* x      = (const float*)d_in[0];
    const float* w_qkv  = (const float*)d_in[1];
    const float* b_qkv  = (const float*)d_in[2];
    const float* w_proj = (const float*)d_in[3];
    const float* b_proj = (const float*)d_in[4];
    const float* rel_h  = (const float*)d_in[5];
    const float* rel_w  = (const float*)d_in[6];
    float* out = (float*)d_out;

    char* base = (char*)d_ws;
    unsigned short* xhi   = (unsigned short*)(base + 0);          // 12,582,912 B
    unsigned short* xlo   = (unsigned short*)(base + 12582912);
    unsigned short* wqh   = (unsigned short*)(base + 25165824);   //  3,538,944 B
    unsigned short* wql   = (unsigned short*)(base + 28704768);
    unsigned short* wph   = (unsigned short*)(base + 32243712);   //  1,179,648 B
    unsigned short* wpl   = (unsigned short*)(base + 33423360);
    unsigned short* qhi   = (unsigned short*)(base + 34603008);   // 12,582,912 B each
    unsigned short* khi   = (unsigned short*)(base + 59768832);
    unsigned short* vhi   = (unsigned short*)(base + 84934656);
    float*          biasH = (float*)(base + 110100480);           // 12,582,912 B
    float*          biasW = (float*)(base + 122683392);
    unsigned short* ohif  = xhi;   // x splits dead after QKV GEMM
    unsigned short* olo   = xlo;

    // 1. split x -> hi/lo
    split_kernel<<<6144, 256, 0, stream>>>(x, xhi, xlo);
    // 2. transpose+split weights
    {
        dim3 gq(C3 / 32, C_ / 32);
        splitT_kernel<<<gq, 256, 0, stream>>>(w_qkv, wqh, wql, C_, C3);
        dim3 gp(C_ / 32, C_ / 32);
        splitT_kernel<<<gp, 256, 0, stream>>>(w_proj, wph, wpl, C_, C_);
    }
    // 3. QKV GEMM (bf16x3) -> plain-bf16 q/k/v [bh][t][64]
    {
        dim3 grid(C3 / 128, 8192 / 128);
        gemm_mfma_kernel<C3, 1><<<grid, 256, 0, stream>>>(xhi, xlo, wqh, wql, b_qkv, nullptr,
                                                          qhi, khi, vhi);
    }
    // 4. rel-pos bias tables
    {
        dim3 grid(32, 96);
        relbias2_kernel<<<grid, 256, 0, stream>>>(qhi, rel_h, rel_w, biasH, biasW);
    }
    // 5. MFMA flash attention (plain bf16)
    {
        dim3 grid(96, SEQ / 64);
        attn3_kernel<<<grid, 256, 0, stream>>>(qhi, khi, vhi, biasH, biasW, ohif, olo);
    }
    // 6. out = attnout @ w_proj + b_proj (bf16x3)
    {
        dim3 grid(C_ / 128, 8192 / 128);
        gemm_mfma_kernel<C_, 0><<<grid, 256, 0, stream>>>(ohif, olo, wph, wpl, b_proj, out,
                                                          nullptr, nullptr, nullptr);
    }
}